// Round 1
// baseline (827.677 us; speedup 1.0000x reference)
//
#include <hip/hip_runtime.h>
#include <math.h>

#define Bb 4
#define Ss 2048
#define Ee 512
#define Hh 8
#define Dd 64
#define HD 512
#define Mm (Bb*Ss)

// ---------------------------------------------------------------------------
// Kernel 1: fused QKV projection.  y = x @ W + b, scattered to [B,H,S,D].
// Tiles: BM=64, BN=64 (one head), BK=32.  256 threads, 4x4 microtile.
// ---------------------------------------------------------------------------
__global__ __launch_bounds__(256) void gemm_qkv(
    const float* __restrict__ x,
    const float* __restrict__ Wq, const float* __restrict__ bq,
    const float* __restrict__ Wk, const float* __restrict__ bk,
    const float* __restrict__ Wv, const float* __restrict__ bv,
    float* __restrict__ q, float* __restrict__ k, float* __restrict__ v)
{
    const int z = blockIdx.z;
    const float* W    = (z == 0) ? Wq : (z == 1) ? Wk : Wv;
    const float* bias = (z == 0) ? bq : (z == 1) ? bk : bv;
    float* dst        = (z == 0) ? q  : (z == 1) ? k  : v;

    const int bm = blockIdx.x;           // 0..127
    const int bn = blockIdx.y;           // 0..7  == head index
    const int tid = threadIdx.x;
    const int tx = tid & 15, ty = tid >> 4;
    const int r0 = ty * 4, c0 = tx * 4;
    const int m0 = bm * 64, n0 = bn * 64;

    __shared__ float As[32][68];   // [k][m], padded
    __shared__ float Bs[32][68];   // [k][n], padded

    float acc[4][4] = {};

    for (int k0 = 0; k0 < Ee; k0 += 32) {
        #pragma unroll
        for (int l = 0; l < 2; ++l) {
            int fi = tid + l * 256;        // 0..511
            int ar = fi >> 3;              // 0..63 (m)
            int ac = (fi & 7) * 4;         // 0..28 (k)
            float4 a = *(const float4*)(x + (size_t)(m0 + ar) * Ee + k0 + ac);
            As[ac + 0][ar] = a.x;
            As[ac + 1][ar] = a.y;
            As[ac + 2][ar] = a.z;
            As[ac + 3][ar] = a.w;
        }
        #pragma unroll
        for (int l = 0; l < 2; ++l) {
            int fi = tid + l * 256;
            int br = fi >> 4;              // 0..31 (k)
            int bc = (fi & 15) * 4;        // 0..60 (n)
            *(float4*)&Bs[br][bc] = *(const float4*)(W + (size_t)(k0 + br) * HD + n0 + bc);
        }
        __syncthreads();
        #pragma unroll
        for (int kk = 0; kk < 32; ++kk) {
            float4 a4 = *(const float4*)&As[kk][r0];
            float4 b4 = *(const float4*)&Bs[kk][c0];
            float av[4]  = {a4.x, a4.y, a4.z, a4.w};
            float bv4[4] = {b4.x, b4.y, b4.z, b4.w};
            #pragma unroll
            for (int i = 0; i < 4; ++i)
                #pragma unroll
                for (int j = 0; j < 4; ++j)
                    acc[i][j] = fmaf(av[i], bv4[j], acc[i][j]);
        }
        __syncthreads();
    }

    float4 bb = *(const float4*)(bias + n0 + c0);
    float bvv[4] = {bb.x, bb.y, bb.z, bb.w};
    #pragma unroll
    for (int i = 0; i < 4; ++i) {
        int m = m0 + r0 + i;
        int b = m >> 11;                 // / 2048
        int s = m & 2047;
        float4 o;
        o.x = acc[i][0] + bvv[0];
        o.y = acc[i][1] + bvv[1];
        o.z = acc[i][2] + bvv[2];
        o.w = acc[i][3] + bvv[3];
        *(float4*)(dst + ((size_t)(b * Hh + bn) * Ss + s) * Dd + c0) = o;
    }
}

// ---------------------------------------------------------------------------
// Kernel 2: flash attention.  One block per (b,h, 64-query tile).
// KP buffer holds K^T [d][key] during scores, then P [q][key] during PV.
// ---------------------------------------------------------------------------
__global__ __launch_bounds__(256) void attn_kernel(
    const float* __restrict__ Q, const float* __restrict__ K,
    const float* __restrict__ V, const int* __restrict__ pad,
    float* __restrict__ Oo)
{
    __shared__ float Qs[64][68];   // [q][d], pre-scaled
    __shared__ float KP[64][68];   // K^T [d][key]  -> later P [q][key]
    __shared__ float Vs[64][68];   // [key][d]
    __shared__ int   padk[64];

    const int bh = blockIdx.y;     // 0..31
    const int b  = bh >> 3;
    const int h  = bh & 7;
    const int qt = blockIdx.x;     // 0..31
    const int tid = threadIdx.x;
    const int tx = tid & 15, ty = tid >> 4;
    const int r0 = ty * 4, c0 = tx * 4;
    const size_t base = (size_t)bh * Ss * Dd;
    const int q0 = qt * 64;
    const float scale = 0.125f;    // 1/sqrt(64)

    #pragma unroll
    for (int l = 0; l < 4; ++l) {
        int fi = tid + l * 256;    // 0..1023
        int r = fi >> 4;           // 0..63
        int c = (fi & 15) * 4;     // 0..60
        float4 a = *(const float4*)(Q + base + (size_t)(q0 + r) * Dd + c);
        a.x *= scale; a.y *= scale; a.z *= scale; a.w *= scale;
        *(float4*)&Qs[r][c] = a;
    }

    bool qpad[4];
    #pragma unroll
    for (int i = 0; i < 4; ++i)
        qpad[i] = pad[b * Ss + q0 + r0 + i] != 0;

    float m_i[4], l_i[4], acc[4][4];
    #pragma unroll
    for (int i = 0; i < 4; ++i) {
        m_i[i] = -INFINITY; l_i[i] = 0.f;
        #pragma unroll
        for (int j = 0; j < 4; ++j) acc[i][j] = 0.f;
    }

    for (int kt = 0; kt < 32; ++kt) {
        const int k0 = kt * 64;
        __syncthreads();           // previous iteration's KP/Vs reads done
        #pragma unroll
        for (int l = 0; l < 4; ++l) {
            int fi = tid + l * 256;
            int r = fi >> 4;
            int c = (fi & 15) * 4;
            float4 kk4 = *(const float4*)(K + base + (size_t)(k0 + r) * Dd + c);
            KP[c + 0][r] = kk4.x;
            KP[c + 1][r] = kk4.y;
            KP[c + 2][r] = kk4.z;
            KP[c + 3][r] = kk4.w;
            *(float4*)&Vs[r][c] = *(const float4*)(V + base + (size_t)(k0 + r) * Dd + c);
        }
        if (tid < 64) padk[tid] = pad[b * Ss + k0 + tid];
        __syncthreads();

        // ---- scores: s = (Q*scale) . K^T ----
        float s[4][4] = {};
        #pragma unroll 4
        for (int d = 0; d < 64; ++d) {
            float4 kd = *(const float4*)&KP[d][c0];
            float kv4[4] = {kd.x, kd.y, kd.z, kd.w};
            float qv[4];
            #pragma unroll
            for (int i = 0; i < 4; ++i) qv[i] = Qs[r0 + i][d];
            #pragma unroll
            for (int i = 0; i < 4; ++i)
                #pragma unroll
                for (int j = 0; j < 4; ++j)
                    s[i][j] = fmaf(qv[i], kv4[j], s[i][j]);
        }

        int kp[4];
        #pragma unroll
        for (int j = 0; j < 4; ++j) kp[j] = padk[c0 + j];
        #pragma unroll
        for (int i = 0; i < 4; ++i)
            #pragma unroll
            for (int j = 0; j < 4; ++j)
                if (qpad[i] || (kp[j] != 0)) s[i][j] = -1e13f;

        // ---- online softmax (row groups of 16 lanes) ----
        float p[4][4];
        #pragma unroll
        for (int i = 0; i < 4; ++i) {
            float t = fmaxf(fmaxf(s[i][0], s[i][1]), fmaxf(s[i][2], s[i][3]));
            t = fmaxf(t, __shfl_xor(t, 8));
            t = fmaxf(t, __shfl_xor(t, 4));
            t = fmaxf(t, __shfl_xor(t, 2));
            t = fmaxf(t, __shfl_xor(t, 1));
            float mnew = fmaxf(m_i[i], t);
            float alpha = __expf(m_i[i] - mnew);   // expf(-inf)=0 first tile
            m_i[i] = mnew;
            float rs = 0.f;
            #pragma unroll
            for (int j = 0; j < 4; ++j) {
                p[i][j] = __expf(s[i][j] - mnew);
                rs += p[i][j];
            }
            rs += __shfl_xor(rs, 8);
            rs += __shfl_xor(rs, 4);
            rs += __shfl_xor(rs, 2);
            rs += __shfl_xor(rs, 1);
            l_i[i] = l_i[i] * alpha + rs;
            #pragma unroll
            for (int j = 0; j < 4; ++j) acc[i][j] *= alpha;
        }

        __syncthreads();           // everyone done reading KP as K^T
        #pragma unroll
        for (int i = 0; i < 4; ++i) {
            float4 pp;
            pp.x = p[i][0]; pp.y = p[i][1]; pp.z = p[i][2]; pp.w = p[i][3];
            *(float4*)&KP[r0 + i][c0] = pp;   // KP now holds P [q][key]
        }
        __syncthreads();

        // ---- O += P . V ----
        #pragma unroll 4
        for (int kx = 0; kx < 64; ++kx) {
            float4 vr = *(const float4*)&Vs[kx][c0];
            float vv4[4] = {vr.x, vr.y, vr.z, vr.w};
            float pv[4];
            #pragma unroll
            for (int i = 0; i < 4; ++i) pv[i] = KP[r0 + i][kx];
            #pragma unroll
            for (int i = 0; i < 4; ++i)
                #pragma unroll
                for (int j = 0; j < 4; ++j)
                    acc[i][j] = fmaf(pv[i], vv4[j], acc[i][j]);
        }
    }

    // epilogue: O /= l, store as [B,S,H*D]
    #pragma unroll
    for (int i = 0; i < 4; ++i) {
        float inv = 1.0f / l_i[i];
        float4 o;
        o.x = acc[i][0] * inv; o.y = acc[i][1] * inv;
        o.z = acc[i][2] * inv; o.w = acc[i][3] * inv;
        *(float4*)(Oo + (size_t)(b * Ss + q0 + r0 + i) * HD + h * Dd + c0) = o;
    }
}

// ---------------------------------------------------------------------------
// Kernel 3: output projection.  out = attn_out @ Wo + bo, row-major [M,E].
// ---------------------------------------------------------------------------
__global__ __launch_bounds__(256) void gemm_out(
    const float* __restrict__ a_in,   // [M, HD]
    const float* __restrict__ Wo, const float* __restrict__ bo,
    float* __restrict__ out)
{
    const int bm = blockIdx.x;
    const int bn = blockIdx.y;
    const int tid = threadIdx.x;
    const int tx = tid & 15, ty = tid >> 4;
    const int r0 = ty * 4, c0 = tx * 4;
    const int m0 = bm * 64, n0 = bn * 64;

    __shared__ float As[32][68];
    __shared__ float Bs[32][68];

    float acc[4][4] = {};

    for (int k0 = 0; k0 < HD; k0 += 32) {
        #pragma unroll
        for (int l = 0; l < 2; ++l) {
            int fi = tid + l * 256;
            int ar = fi >> 3;
            int ac = (fi & 7) * 4;
            float4 a = *(const float4*)(a_in + (size_t)(m0 + ar) * HD + k0 + ac);
            As[ac + 0][ar] = a.x;
            As[ac + 1][ar] = a.y;
            As[ac + 2][ar] = a.z;
            As[ac + 3][ar] = a.w;
        }
        #pragma unroll
        for (int l = 0; l < 2; ++l) {
            int fi = tid + l * 256;
            int br = fi >> 4;
            int bc = (fi & 15) * 4;
            *(float4*)&Bs[br][bc] = *(const float4*)(Wo + (size_t)(k0 + br) * Ee + n0 + bc);
        }
        __syncthreads();
        #pragma unroll
        for (int kk = 0; kk < 32; ++kk) {
            float4 a4 = *(const float4*)&As[kk][r0];
            float4 b4 = *(const float4*)&Bs[kk][c0];
            float av[4]  = {a4.x, a4.y, a4.z, a4.w};
            float bv4[4] = {b4.x, b4.y, b4.z, b4.w};
            #pragma unroll
            for (int i = 0; i < 4; ++i)
                #pragma unroll
                for (int j = 0; j < 4; ++j)
                    acc[i][j] = fmaf(av[i], bv4[j], acc[i][j]);
        }
        __syncthreads();
    }

    float4 bb = *(const float4*)(bo + n0 + c0);
    float bvv[4] = {bb.x, bb.y, bb.z, bb.w};
    #pragma unroll
    for (int i = 0; i < 4; ++i) {
        int m = m0 + r0 + i;
        float4 o;
        o.x = acc[i][0] + bvv[0];
        o.y = acc[i][1] + bvv[1];
        o.z = acc[i][2] + bvv[2];
        o.w = acc[i][3] + bvv[3];
        *(float4*)(out + (size_t)m * Ee + n0 + c0) = o;
    }
}

extern "C" void kernel_launch(void* const* d_in, const int* in_sizes, int n_in,
                              void* d_out, int out_size, void* d_ws, size_t ws_size,
                              hipStream_t stream) {
    const float* x   = (const float*)d_in[0];
    const int*   pad = (const int*)  d_in[1];
    const float* Wq  = (const float*)d_in[2];
    const float* bq  = (const float*)d_in[3];
    const float* Wk  = (const float*)d_in[4];
    const float* bk  = (const float*)d_in[5];
    const float* Wv  = (const float*)d_in[6];
    const float* bv  = (const float*)d_in[7];
    const float* Wo  = (const float*)d_in[8];
    const float* bo  = (const float*)d_in[9];
    float* out = (float*)d_out;

    const size_t tsz = (size_t)Bb * Hh * Ss * Dd;   // 4,194,304 floats
    float* q  = (float*)d_ws;
    float* k  = q + tsz;
    float* v  = k + tsz;
    float* ao = v + tsz;

    dim3 g1(Mm / 64, HD / 64, 3);
    gemm_qkv<<<g1, 256, 0, stream>>>(x, Wq, bq, Wk, bk, Wv, bv, q, k, v);

    dim3 g2(Ss / 64, Bb * Hh);
    attn_kernel<<<g2, 256, 0, stream>>>(q, k, v, pad, ao);

    dim3 g3(Mm / 64, Ee / 64);
    gemm_out<<<g3, 256, 0, stream>>>(ao, Wo, bo, out);
}

// Round 3
// 280.295 us; speedup vs baseline: 2.9529x; 2.9529x over previous
//
#include <hip/hip_runtime.h>
#include <math.h>

#define Bb 4
#define Ss 2048
#define Ee 512
#define Hh 8
#define Dd 64
#define HD 512
#define Mm (Bb*Ss)

using bf16x8 = __attribute__((ext_vector_type(8))) short;
using f32x4  = __attribute__((ext_vector_type(4))) float;

__device__ inline unsigned short f2bf(float f) {
    unsigned int u = __float_as_uint(f);
    unsigned int r = (u + 0x7fffu + ((u >> 16) & 1u)) >> 16;
    return (unsigned short)r;
}
__device__ inline unsigned int packbf(float lo, float hi) {
    return (unsigned int)f2bf(lo) | ((unsigned int)f2bf(hi) << 16);
}

// ---------------------------------------------------------------------------
// Kernel 0: convert+transpose weights.  Wt[w][n][k] (bf16) = W[w][k][n] (fp32)
// ---------------------------------------------------------------------------
__global__ __launch_bounds__(256) void wconv(
    const float* __restrict__ Wq, const float* __restrict__ Wk,
    const float* __restrict__ Wv, const float* __restrict__ Wo,
    unsigned short* __restrict__ Wt)
{
    const int w = blockIdx.z;
    const float* W = (w == 0) ? Wq : (w == 1) ? Wk : (w == 2) ? Wv : Wo;
    const int tk0 = blockIdx.x * 64, tn0 = blockIdx.y * 64;
    const int tid = threadIdx.x;
    __shared__ float T[64][68];   // 272B rows, 16B aligned

    #pragma unroll
    for (int l = 0; l < 4; ++l) {
        int fi = tid + l * 256;            // 0..1023
        int r = fi >> 4, c4 = (fi & 15) * 4;
        *(float4*)&T[r][c4] = *(const float4*)(W + (size_t)(tk0 + r) * Ee + tn0 + c4);
    }
    __syncthreads();
    #pragma unroll
    for (int l = 0; l < 4; ++l) {
        int fi = tid + l * 256;
        int r2 = fi >> 4, c4 = (fi & 15) * 4;   // r2 = n-local, c4 = k-local
        ushort4 o;
        o.x = f2bf(T[c4 + 0][r2]);
        o.y = f2bf(T[c4 + 1][r2]);
        o.z = f2bf(T[c4 + 2][r2]);
        o.w = f2bf(T[c4 + 3][r2]);
        *(ushort4*)(Wt + (size_t)w * 262144 + (size_t)(tn0 + r2) * Ee + tk0 + c4) = o;
    }
}

// ---------------------------------------------------------------------------
// Kernel 1: QKV projection, bf16 MFMA.  128x128 tile, BK=32, 4 waves (2x2).
// Outputs q/k/v bf16 [B,H,S,D]; q pre-scaled by 1/sqrt(D).
// ---------------------------------------------------------------------------
__global__ __launch_bounds__(256) void gemm_qkv(
    const float* __restrict__ x, const unsigned short* __restrict__ Wt,
    const float* __restrict__ bq, const float* __restrict__ bk, const float* __restrict__ bv,
    unsigned short* __restrict__ qo, unsigned short* __restrict__ ko, unsigned short* __restrict__ vo)
{
    const int z = blockIdx.z;
    const unsigned short* Wz = Wt + (size_t)z * 262144;
    const float* bias = (z == 0) ? bq : (z == 1) ? bk : bv;
    unsigned short* dst = (z == 0) ? qo : (z == 1) ? ko : vo;

    const int m0 = blockIdx.x * 128, n0 = blockIdx.y * 128;
    const int tid = threadIdx.x, lane = tid & 63, wv = tid >> 6;
    const int quad = lane >> 4, l15 = lane & 15;
    const int wm = (wv >> 1) * 64, wn = (wv & 1) * 64;

    __shared__ unsigned short As[128][32];
    __shared__ unsigned short Bs[128][32];

    f32x4 acc[4][4] = {};

    for (int k0 = 0; k0 < Ee; k0 += 32) {
        #pragma unroll
        for (int l = 0; l < 4; ++l) {              // A: 128x32 fp32 -> bf16
            int fi = tid + l * 256;
            int r = fi >> 3, c = (fi & 7) * 4;
            float4 a = *(const float4*)(x + (size_t)(m0 + r) * Ee + k0 + c);
            ushort4 o; o.x = f2bf(a.x); o.y = f2bf(a.y); o.z = f2bf(a.z); o.w = f2bf(a.w);
            *(ushort4*)&As[r][c] = o;
        }
        #pragma unroll
        for (int l = 0; l < 2; ++l) {              // B: 128x32 bf16 copy
            int ci = tid + l * 256;
            int r = ci >> 2, ch = (ci & 3) * 8;
            *(uint4*)&Bs[r][ch] = *(const uint4*)(Wz + (size_t)(n0 + r) * Ee + k0 + ch);
        }
        __syncthreads();

        bf16x8 af[4], bfr[4];
        #pragma unroll
        for (int ms = 0; ms < 4; ++ms) af[ms] = *(const bf16x8*)&As[wm + ms * 16 + l15][quad * 8];
        #pragma unroll
        for (int ns = 0; ns < 4; ++ns) bfr[ns] = *(const bf16x8*)&Bs[wn + ns * 16 + l15][quad * 8];
        #pragma unroll
        for (int ms = 0; ms < 4; ++ms)
            #pragma unroll
            for (int ns = 0; ns < 4; ++ns)
                acc[ms][ns] = __builtin_amdgcn_mfma_f32_16x16x32_bf16(af[ms], bfr[ns], acc[ms][ns], 0, 0, 0);
        __syncthreads();
    }

    // epilogue: scatter to [B,H,S,D] bf16
    #pragma unroll
    for (int ns = 0; ns < 4; ++ns) {
        int col = n0 + wn + ns * 16 + l15;         // 0..511
        float bb = bias[col];
        int h = col >> 6, d = col & 63;
        #pragma unroll
        for (int ms = 0; ms < 4; ++ms) {
            #pragma unroll
            for (int r = 0; r < 4; ++r) {
                int m = m0 + wm + ms * 16 + quad * 4 + r;
                int b = m >> 11, s = m & 2047;
                float val = acc[ms][ns][r] + bb;
                if (z == 0) val *= 0.125f;
                dst[((size_t)(b * Hh + h) * Ss + s) * Dd + d] = f2bf(val);
            }
        }
    }
}

// ---------------------------------------------------------------------------
// Kernel 2: V transpose.  v [BH,S,D] bf16 -> vt [BH,D,S] bf16.
// 64 rows x 64 cols bf16 tile = 512 uint4 chunks (8 chunks per row).
// ---------------------------------------------------------------------------
__global__ __launch_bounds__(256) void vtrans(
    const unsigned short* __restrict__ v, unsigned short* __restrict__ vt)
{
    const int bh = blockIdx.y, s0 = blockIdx.x * 64;
    const int tid = threadIdx.x;
    __shared__ unsigned short T[64][72];   // 144B rows

    #pragma unroll
    for (int l = 0; l < 2; ++l) {
        int ci = tid + l * 256;            // 0..511
        int r = ci >> 3, ch = (ci & 7) * 8;   // 64 rows x 8 chunks
        *(uint4*)&T[r][ch] = *(const uint4*)(v + ((size_t)bh * Ss + s0 + r) * Dd + ch);
    }
    __syncthreads();
    #pragma unroll
    for (int l = 0; l < 2; ++l) {
        int ci = tid + l * 256;
        int dr = ci >> 3, sc = (ci & 7) * 8;  // dr = d-row 0..63, sc = key 0..56
        union { unsigned short u[8]; uint4 q; } o;
        #pragma unroll
        for (int j = 0; j < 8; ++j) o.u[j] = T[sc + j][dr];
        *(uint4*)(vt + ((size_t)bh * Dd + dr) * Ss + s0 + sc) = o.q;
    }
}

// ---------------------------------------------------------------------------
// Kernel 3: flash attention, bf16 MFMA.  Block = 4 waves x 16 q-rows = 64 q.
// K-tiles of 64 keys.  Ks/Vs: [kstep][row][32] bf16 (64B rows, even banks).
// ---------------------------------------------------------------------------
__global__ __launch_bounds__(256) void attn(
    const unsigned short* __restrict__ q, const unsigned short* __restrict__ k,
    const unsigned short* __restrict__ vt, const int* __restrict__ pad,
    unsigned short* __restrict__ ao)
{
    __shared__ unsigned short Ks[2][64][32];
    __shared__ unsigned short Vs[2][64][32];
    __shared__ unsigned short Ps[4][16][68];
    __shared__ int padk[64];

    const int tid = threadIdx.x, wv = tid >> 6, lane = tid & 63;
    const int quad = lane >> 4, l15 = lane & 15;
    const int bh = blockIdx.y, b = bh >> 3, h = bh & 7;
    const int q0 = blockIdx.x * 64 + wv * 16;

    const unsigned short* qb = q + (size_t)bh * Ss * Dd;
    const unsigned short* kb = k + (size_t)bh * Ss * Dd;
    const unsigned short* vb = vt + (size_t)bh * Dd * Ss;

    bf16x8 aq0 = *(const bf16x8*)(qb + (size_t)(q0 + l15) * Dd + quad * 8);
    bf16x8 aq1 = *(const bf16x8*)(qb + (size_t)(q0 + l15) * Dd + 32 + quad * 8);

    bool qp[4];
    #pragma unroll
    for (int r = 0; r < 4; ++r) qp[r] = pad[b * Ss + q0 + quad * 4 + r] != 0;

    float mi[4], li[4];
    f32x4 oacc[4] = {};
    #pragma unroll
    for (int r = 0; r < 4; ++r) { mi[r] = -INFINITY; li[r] = 0.f; }

    for (int kt = 0; kt < 32; ++kt) {
        const int k0 = kt * 64;
        __syncthreads();
        #pragma unroll
        for (int l = 0; l < 2; ++l) {
            int ci = tid + l * 256;            // 0..511
            int s = ci >> 8, row = (ci >> 2) & 63, ch = (ci & 3) * 8;
            *(uint4*)&Ks[s][row][ch] = *(const uint4*)(kb + (size_t)(k0 + row) * Dd + s * 32 + ch);
            *(uint4*)&Vs[s][row][ch] = *(const uint4*)(vb + (size_t)row * Ss + k0 + s * 32 + ch);
        }
        if (tid < 64) padk[tid] = pad[b * Ss + k0 + tid];
        __syncthreads();

        // ---- S = Q K^T ----
        f32x4 sa[4];
        #pragma unroll
        for (int nt = 0; nt < 4; ++nt) {
            bf16x8 b0 = *(const bf16x8*)&Ks[0][nt * 16 + l15][quad * 8];
            bf16x8 b1 = *(const bf16x8*)&Ks[1][nt * 16 + l15][quad * 8];
            f32x4 zz = {0.f, 0.f, 0.f, 0.f};
            zz = __builtin_amdgcn_mfma_f32_16x16x32_bf16(aq0, b0, zz, 0, 0, 0);
            zz = __builtin_amdgcn_mfma_f32_16x16x32_bf16(aq1, b1, zz, 0, 0, 0);
            sa[nt] = zz;
        }

        // ---- mask ----
        #pragma unroll
        for (int nt = 0; nt < 4; ++nt) {
            bool kp = padk[nt * 16 + l15] != 0;
            #pragma unroll
            for (int r = 0; r < 4; ++r)
                if (kp || qp[r]) sa[nt][r] = -1e13f;
        }

        // ---- online softmax (row = quad*4+r, cols across 16 lanes of quad) ----
        float alpha[4];
        #pragma unroll
        for (int r = 0; r < 4; ++r) {
            float t = fmaxf(fmaxf(sa[0][r], sa[1][r]), fmaxf(sa[2][r], sa[3][r]));
            t = fmaxf(t, __shfl_xor(t, 1));
            t = fmaxf(t, __shfl_xor(t, 2));
            t = fmaxf(t, __shfl_xor(t, 4));
            t = fmaxf(t, __shfl_xor(t, 8));
            float mnew = fmaxf(mi[r], t);
            alpha[r] = __expf(mi[r] - mnew);
            mi[r] = mnew;
            float rs = 0.f;
            #pragma unroll
            for (int nt = 0; nt < 4; ++nt) { sa[nt][r] = __expf(sa[nt][r] - mnew); rs += sa[nt][r]; }
            rs += __shfl_xor(rs, 1);
            rs += __shfl_xor(rs, 2);
            rs += __shfl_xor(rs, 4);
            rs += __shfl_xor(rs, 8);
            li[r] = li[r] * alpha[r] + rs;
        }
        #pragma unroll
        for (int nt = 0; nt < 4; ++nt)
            #pragma unroll
            for (int r = 0; r < 4; ++r) oacc[nt][r] *= alpha[r];

        // ---- P -> LDS (bf16-pair packed b32 writes), wave-private ----
        {
            int pcol = (l15 >> 1) * 2;
            int ntbase = (l15 & 1) * 2;
            #pragma unroll
            for (int r = 0; r < 4; ++r) {
                int qrow = quad * 4 + r;
                unsigned int pr[4];
                #pragma unroll
                for (int nt = 0; nt < 4; ++nt) {
                    float vme = sa[nt][r];
                    float vot = __shfl_xor(vme, 1);
                    float lo = (l15 & 1) ? vot : vme;
                    float hi = (l15 & 1) ? vme : vot;
                    pr[nt] = packbf(lo, hi);
                }
                *(unsigned int*)&Ps[wv][qrow][(ntbase + 0) * 16 + pcol] = pr[ntbase + 0];
                *(unsigned int*)&Ps[wv][qrow][(ntbase + 1) * 16 + pcol] = pr[ntbase + 1];
            }
        }

        // ---- O += P V ----
        union U8 { ushort4 h[2]; bf16x8 v8; };
        U8 ap0, ap1;
        ap0.h[0] = *(const ushort4*)&Ps[wv][l15][quad * 8];
        ap0.h[1] = *(const ushort4*)&Ps[wv][l15][quad * 8 + 4];
        ap1.h[0] = *(const ushort4*)&Ps[wv][l15][32 + quad * 8];
        ap1.h[1] = *(const ushort4*)&Ps[wv][l15][32 + quad * 8 + 4];
        #pragma unroll
        for (int nt = 0; nt < 4; ++nt) {
            bf16x8 v0 = *(const bf16x8*)&Vs[0][nt * 16 + l15][quad * 8];
            bf16x8 v1 = *(const bf16x8*)&Vs[1][nt * 16 + l15][quad * 8];
            oacc[nt] = __builtin_amdgcn_mfma_f32_16x16x32_bf16(ap0.v8, v0, oacc[nt], 0, 0, 0);
            oacc[nt] = __builtin_amdgcn_mfma_f32_16x16x32_bf16(ap1.v8, v1, oacc[nt], 0, 0, 0);
        }
    }

    // epilogue: ao [B,S,HD] bf16
    #pragma unroll
    for (int r = 0; r < 4; ++r) {
        float inv = 1.0f / li[r];
        int srow = q0 + quad * 4 + r;
        #pragma unroll
        for (int nt = 0; nt < 4; ++nt)
            ao[((size_t)b * Ss + srow) * HD + h * Dd + nt * 16 + l15] = f2bf(oacc[nt][r] * inv);
    }
}

// ---------------------------------------------------------------------------
// Kernel 4: output projection.  A = ao bf16 [M,HD], B = Wo^T bf16, out fp32.
// ---------------------------------------------------------------------------
__global__ __launch_bounds__(256) void gemm_out(
    const unsigned short* __restrict__ a_in, const unsigned short* __restrict__ Wt,
    const float* __restrict__ bo, float* __restrict__ out)
{
    const unsigned short* Wz = Wt + (size_t)3 * 262144;
    const int m0 = blockIdx.x * 128, n0 = blockIdx.y * 128;
    const int tid = threadIdx.x, lane = tid & 63, wv = tid >> 6;
    const int quad = lane >> 4, l15 = lane & 15;
    const int wm = (wv >> 1) * 64, wn = (wv & 1) * 64;

    __shared__ unsigned short As[128][32];
    __shared__ unsigned short Bs[128][32];

    f32x4 acc[4][4] = {};

    for (int k0 = 0; k0 < HD; k0 += 32) {
        #pragma unroll
        for (int l = 0; l < 2; ++l) {
            int ci = tid + l * 256;
            int r = ci >> 2, ch = (ci & 3) * 8;
            *(uint4*)&As[r][ch] = *(const uint4*)(a_in + (size_t)(m0 + r) * HD + k0 + ch);
            *(uint4*)&Bs[r][ch] = *(const uint4*)(Wz + (size_t)(n0 + r) * HD + k0 + ch);
        }
        __syncthreads();
        bf16x8 af[4], bfr[4];
        #pragma unroll
        for (int ms = 0; ms < 4; ++ms) af[ms] = *(const bf16x8*)&As[wm + ms * 16 + l15][quad * 8];
        #pragma unroll
        for (int ns = 0; ns < 4; ++ns) bfr[ns] = *(const bf16x8*)&Bs[wn + ns * 16 + l15][quad * 8];
        #pragma unroll
        for (int ms = 0; ms < 4; ++ms)
            #pragma unroll
            for (int ns = 0; ns < 4; ++ns)
                acc[ms][ns] = __builtin_amdgcn_mfma_f32_16x16x32_bf16(af[ms], bfr[ns], acc[ms][ns], 0, 0, 0);
        __syncthreads();
    }

    #pragma unroll
    for (int ns = 0; ns < 4; ++ns) {
        int col = n0 + wn + ns * 16 + l15;
        float bb = bo[col];
        #pragma unroll
        for (int ms = 0; ms < 4; ++ms) {
            #pragma unroll
            for (int r = 0; r < 4; ++r) {
                int m = m0 + wm + ms * 16 + quad * 4 + r;
                out[(size_t)m * Ee + col] = acc[ms][ns][r] + bb;
            }
        }
    }
}

extern "C" void kernel_launch(void* const* d_in, const int* in_sizes, int n_in,
                              void* d_out, int out_size, void* d_ws, size_t ws_size,
                              hipStream_t stream) {
    const float* x   = (const float*)d_in[0];
    const int*   pad = (const int*)  d_in[1];
    const float* Wq  = (const float*)d_in[2];
    const float* bq  = (const float*)d_in[3];
    const float* Wk  = (const float*)d_in[4];
    const float* bk  = (const float*)d_in[5];
    const float* Wv  = (const float*)d_in[6];
    const float* bv  = (const float*)d_in[7];
    const float* Wo  = (const float*)d_in[8];
    const float* bo  = (const float*)d_in[9];
    float* out = (float*)d_out;

    unsigned short* Wt  = (unsigned short*)d_ws;        // 4*512*512 = 1,048,576
    unsigned short* qb  = Wt + 1048576;                 // 4,194,304 each
    unsigned short* kb  = qb + 4194304;
    unsigned short* vb  = kb + 4194304;
    unsigned short* vtb = vb + 4194304;
    unsigned short* aob = vtb + 4194304;

    dim3 g0(8, 8, 4);
    wconv<<<g0, 256, 0, stream>>>(Wq, Wk, Wv, Wo, Wt);

    dim3 g1(Mm / 128, HD / 128, 3);
    gemm_qkv<<<g1, 256, 0, stream>>>(x, Wt, bq, bk, bv, qb, kb, vb);

    dim3 g2(Ss / 64, Bb * Hh);
    vtrans<<<g2, 256, 0, stream>>>(vb, vtb);

    dim3 g3(Ss / 64, Bb * Hh);
    attn<<<g3, 256, 0, stream>>>(qb, kb, vtb, pad, aob);

    dim3 g4(Mm / 128, Ee / 128);
    gemm_out<<<g4, 256, 0, stream>>>(aob, Wt, bo, out);
}

// Round 4
// 217.446 us; speedup vs baseline: 3.8064x; 1.2890x over previous
//
#include <hip/hip_runtime.h>
#include <hip/hip_bf16.h>
#include <math.h>

#define Bb 4
#define Ss 2048
#define Ee 512
#define Hh 8
#define Dd 64
#define HD 512
#define Mm (Bb*Ss)

using bf16x8 = __attribute__((ext_vector_type(8))) short;
using f32x4  = __attribute__((ext_vector_type(4))) float;

__device__ inline unsigned short f2bf(float f) {
    unsigned int u = __float_as_uint(f);
    unsigned int r = (u + 0x7fffu + ((u >> 16) & 1u)) >> 16;
    return (unsigned short)r;
}
__device__ inline float bf2f(unsigned short u) {
    return __uint_as_float((unsigned int)u << 16);
}
// packed 2xfp32 -> 2xbf16 (v_cvt_pk_bf16_f32, RNE)
__device__ inline unsigned int cvtpk(float a, float b) {
    float2 t; t.x = a; t.y = b;
    union { __hip_bfloat162 h; unsigned int u; } z;
    z.h = __float22bfloat162_rn(t);
    return z.u;
}

// ---------------------------------------------------------------------------
// Kernel 0: convert+transpose weights.  Wt[w][n][k] (bf16) = W[w][k][n] (fp32)
// ---------------------------------------------------------------------------
__global__ __launch_bounds__(256) void wconv(
    const float* __restrict__ Wq, const float* __restrict__ Wk,
    const float* __restrict__ Wv, const float* __restrict__ Wo,
    unsigned short* __restrict__ Wt)
{
    const int w = blockIdx.z;
    const float* W = (w == 0) ? Wq : (w == 1) ? Wk : (w == 2) ? Wv : Wo;
    const int tk0 = blockIdx.x * 64, tn0 = blockIdx.y * 64;
    const int tid = threadIdx.x;
    __shared__ float T[64][68];

    #pragma unroll
    for (int l = 0; l < 4; ++l) {
        int fi = tid + l * 256;
        int r = fi >> 4, c4 = (fi & 15) * 4;
        *(float4*)&T[r][c4] = *(const float4*)(W + (size_t)(tk0 + r) * Ee + tn0 + c4);
    }
    __syncthreads();
    #pragma unroll
    for (int l = 0; l < 4; ++l) {
        int fi = tid + l * 256;
        int r2 = fi >> 4, c4 = (fi & 15) * 4;
        uint2 o;
        o.x = cvtpk(T[c4 + 0][r2], T[c4 + 1][r2]);
        o.y = cvtpk(T[c4 + 2][r2], T[c4 + 3][r2]);
        *(uint2*)(Wt + (size_t)w * 262144 + (size_t)(tn0 + r2) * Ee + tk0 + c4) = o;
    }
}

// ---------------------------------------------------------------------------
// Kernel 1: QKV projection, bf16 MFMA.  128x128 tile, BK=32, 4 waves (2x2).
// Outputs q/k/v bf16 [B,H,S,D]; q pre-scaled by 1/sqrt(D).
// ---------------------------------------------------------------------------
__global__ __launch_bounds__(256) void gemm_qkv(
    const float* __restrict__ x, const unsigned short* __restrict__ Wt,
    const float* __restrict__ bq, const float* __restrict__ bk, const float* __restrict__ bv,
    unsigned short* __restrict__ qo, unsigned short* __restrict__ ko, unsigned short* __restrict__ vo)
{
    const int z = blockIdx.z;
    const unsigned short* Wz = Wt + (size_t)z * 262144;
    const float* bias = (z == 0) ? bq : (z == 1) ? bk : bv;
    unsigned short* dst = (z == 0) ? qo : (z == 1) ? ko : vo;

    const int m0 = blockIdx.x * 128, n0 = blockIdx.y * 128;
    const int tid = threadIdx.x, lane = tid & 63, wv = tid >> 6;
    const int quad = lane >> 4, l15 = lane & 15;
    const int wm = (wv >> 1) * 64, wn = (wv & 1) * 64;

    __shared__ unsigned short As[128][32];
    __shared__ unsigned short Bs[128][32];

    f32x4 acc[4][4] = {};

    for (int k0 = 0; k0 < Ee; k0 += 32) {
        #pragma unroll
        for (int l = 0; l < 4; ++l) {              // A: 128x32 fp32 -> bf16 (pk cvt)
            int fi = tid + l * 256;
            int r = fi >> 3, c = (fi & 7) * 4;
            float4 a = *(const float4*)(x + (size_t)(m0 + r) * Ee + k0 + c);
            uint2 o; o.x = cvtpk(a.x, a.y); o.y = cvtpk(a.z, a.w);
            *(uint2*)&As[r][c] = o;
        }
        #pragma unroll
        for (int l = 0; l < 2; ++l) {              // B: 128x32 bf16 copy
            int ci = tid + l * 256;
            int r = ci >> 2, ch = (ci & 3) * 8;
            *(uint4*)&Bs[r][ch] = *(const uint4*)(Wz + (size_t)(n0 + r) * Ee + k0 + ch);
        }
        __syncthreads();

        bf16x8 af[4], bfr[4];
        #pragma unroll
        for (int ms = 0; ms < 4; ++ms) af[ms] = *(const bf16x8*)&As[wm + ms * 16 + l15][quad * 8];
        #pragma unroll
        for (int ns = 0; ns < 4; ++ns) bfr[ns] = *(const bf16x8*)&Bs[wn + ns * 16 + l15][quad * 8];
        #pragma unroll
        for (int ms = 0; ms < 4; ++ms)
            #pragma unroll
            for (int ns = 0; ns < 4; ++ns)
                acc[ms][ns] = __builtin_amdgcn_mfma_f32_16x16x32_bf16(af[ms], bfr[ns], acc[ms][ns], 0, 0, 0);
        __syncthreads();
    }

    #pragma unroll
    for (int ns = 0; ns < 4; ++ns) {
        int col = n0 + wn + ns * 16 + l15;
        float bb = bias[col];
        int h = col >> 6, d = col & 63;
        #pragma unroll
        for (int ms = 0; ms < 4; ++ms) {
            #pragma unroll
            for (int r = 0; r < 4; ++r) {
                int m = m0 + wm + ms * 16 + quad * 4 + r;
                int b = m >> 11, s = m & 2047;
                float val = acc[ms][ns][r] + bb;
                if (z == 0) val *= 0.125f;
                dst[((size_t)(b * Hh + h) * Ss + s) * Dd + d] = f2bf(val);
            }
        }
    }
}

// ---------------------------------------------------------------------------
// Kernel 2: per-batch compaction index scan.  idx[b][j] = j-th unmasked s.
// ---------------------------------------------------------------------------
__global__ __launch_bounds__(256) void scan_pad(
    const int* __restrict__ pad, int* __restrict__ idx, int* __restrict__ cnt)
{
    const int b = blockIdx.x, tid = threadIdx.x;
    __shared__ int sc[256];
    int loc[8], c = 0;
    #pragma unroll
    for (int j = 0; j < 8; ++j) {
        loc[j] = pad[b * Ss + tid * 8 + j];
        c += (loc[j] == 0);
    }
    sc[tid] = c;
    __syncthreads();
    for (int s = 1; s < 256; s <<= 1) {
        int v = (tid >= s) ? sc[tid - s] : 0;
        __syncthreads();
        sc[tid] += v;
        __syncthreads();
    }
    int off = b * Ss + sc[tid] - c;
    #pragma unroll
    for (int j = 0; j < 8; ++j)
        if (loc[j] == 0) idx[off++] = tid * 8 + j;
    if (tid == 255) cnt[b] = sc[255];
}

// ---------------------------------------------------------------------------
// Kernel 3: vmean[bh][d] = mean over ALL s of v[bh][s][d]  (masked-query rows)
// ---------------------------------------------------------------------------
__global__ __launch_bounds__(256) void vmeank(
    const unsigned short* __restrict__ vb, float* __restrict__ vmean)
{
    const int bh = blockIdx.x, tid = threadIdx.x;
    const int chunk = tid & 7, part = tid >> 3;      // 32 parts x 64 rows
    __shared__ float sm[32][64];
    float a8[8] = {};
    const unsigned short* p = vb + (size_t)bh * Ss * Dd + chunk * 8;
    for (int i = 0; i < 64; ++i) {
        union { unsigned short u[8]; uint4 q; } t;
        t.q = *(const uint4*)(p + (size_t)(part * 64 + i) * Dd);
        #pragma unroll
        for (int j = 0; j < 8; ++j) a8[j] += bf2f(t.u[j]);
    }
    #pragma unroll
    for (int j = 0; j < 8; ++j) sm[part][chunk * 8 + j] = a8[j];
    __syncthreads();
    if (tid < 64) {
        float s = 0.f;
        #pragma unroll 8
        for (int pp = 0; pp < 32; ++pp) s += sm[pp][tid];
        vmean[bh * Dd + tid] = s * (1.0f / 2048.0f);
    }
}

// ---------------------------------------------------------------------------
// Kernel 4: gather-compact K and V^T to dense unmasked key sets.
// kc[bh][j][d], vtc[bh][d][j]; tail (j >= cnt, within 64-tile) zero-filled.
// ---------------------------------------------------------------------------
__global__ __launch_bounds__(256) void compact(
    const unsigned short* __restrict__ kb, const unsigned short* __restrict__ vb,
    const int* __restrict__ idx, const int* __restrict__ cnt,
    unsigned short* __restrict__ kc, unsigned short* __restrict__ vtc)
{
    const int bh = blockIdx.y, b = bh >> 3;
    const int cntb = cnt[b];
    const int j0 = blockIdx.x * 64;
    if (j0 >= cntb) return;
    const int tid = threadIdx.x;
    const unsigned short* kbb = kb + (size_t)bh * Ss * Dd;
    const unsigned short* vbb = vb + (size_t)bh * Ss * Dd;
    __shared__ unsigned short T[64][72];
    __shared__ int sidx[64];
    if (tid < 64) {
        int j = j0 + tid;
        sidx[tid] = (j < cntb) ? idx[b * Ss + j] : -1;
    }
    __syncthreads();
    #pragma unroll
    for (int l = 0; l < 2; ++l) {
        int ci = tid + l * 256;
        int r = ci >> 3, ch = (ci & 7) * 8;
        int s = sidx[r];
        uint4 kd = {0, 0, 0, 0}, vd = {0, 0, 0, 0};
        if (s >= 0) {
            kd = *(const uint4*)(kbb + (size_t)s * Dd + ch);
            vd = *(const uint4*)(vbb + (size_t)s * Dd + ch);
        }
        *(uint4*)(kc + ((size_t)bh * Ss + j0 + r) * Dd + ch) = kd;
        *(uint4*)&T[r][ch] = vd;
    }
    __syncthreads();
    #pragma unroll
    for (int l = 0; l < 2; ++l) {
        int ci = tid + l * 256;
        int dr = ci >> 3, sc8 = (ci & 7) * 8;
        union { unsigned short u[8]; uint4 q; } o;
        #pragma unroll
        for (int j = 0; j < 8; ++j) o.u[j] = T[sc8 + j][dr];
        *(uint4*)(vtc + ((size_t)bh * Dd + dr) * Ss + j0 + sc8) = o.q;
    }
}

// ---------------------------------------------------------------------------
// Kernel 5: flash attention over compacted keys.  4 waves x 16 q-rows.
// No in-loop masking except tail-tile validity; masked queries -> vmean.
// ---------------------------------------------------------------------------
__global__ __launch_bounds__(256) void attn(
    const unsigned short* __restrict__ q, const unsigned short* __restrict__ kc,
    const unsigned short* __restrict__ vtc, const int* __restrict__ pad,
    const int* __restrict__ cnt, const float* __restrict__ vmean,
    unsigned short* __restrict__ ao)
{
    __shared__ unsigned short Ks[2][64][32];
    __shared__ unsigned short Vs[2][64][32];
    __shared__ float Ps[4][16][68];

    const int tid = threadIdx.x, wv = tid >> 6, lane = tid & 63;
    const int quad = lane >> 4, l15 = lane & 15;
    const int bh = blockIdx.y, b = bh >> 3, h = bh & 7;
    const int q0 = blockIdx.x * 64 + wv * 16;
    const float C = 1.44269504f;      // log2(e)

    const unsigned short* qb  = q   + (size_t)bh * Ss * Dd;
    const unsigned short* kcb = kc  + (size_t)bh * Ss * Dd;
    const unsigned short* vtb = vtc + (size_t)bh * Dd * Ss;

    const int cntb = cnt[b];
    const int ktiles = (cntb + 63) >> 6;

    bf16x8 aq0 = *(const bf16x8*)(qb + (size_t)(q0 + l15) * Dd + quad * 8);
    bf16x8 aq1 = *(const bf16x8*)(qb + (size_t)(q0 + l15) * Dd + 32 + quad * 8);

    bool qp[4];
    #pragma unroll
    for (int r = 0; r < 4; ++r) qp[r] = pad[b * Ss + q0 + quad * 4 + r] != 0;

    float mi[4], li[4];
    f32x4 oacc[4] = {};
    #pragma unroll
    for (int r = 0; r < 4; ++r) { mi[r] = -INFINITY; li[r] = 0.f; }

    for (int kt = 0; kt < ktiles; ++kt) {
        const int k0 = kt * 64;
        __syncthreads();
        #pragma unroll
        for (int l = 0; l < 2; ++l) {
            int ci = tid + l * 256;
            int s = ci >> 8, row = (ci >> 2) & 63, ch = (ci & 3) * 8;
            *(uint4*)&Ks[s][row][ch] = *(const uint4*)(kcb + (size_t)(k0 + row) * Dd + s * 32 + ch);
            *(uint4*)&Vs[s][row][ch] = *(const uint4*)(vtb + (size_t)row * Ss + k0 + s * 32 + ch);
        }
        __syncthreads();

        // ---- S = Q K^T ----
        f32x4 sa[4];
        #pragma unroll
        for (int nt = 0; nt < 4; ++nt) {
            bf16x8 b0 = *(const bf16x8*)&Ks[0][nt * 16 + l15][quad * 8];
            bf16x8 b1 = *(const bf16x8*)&Ks[1][nt * 16 + l15][quad * 8];
            f32x4 zz = {0.f, 0.f, 0.f, 0.f};
            zz = __builtin_amdgcn_mfma_f32_16x16x32_bf16(aq0, b0, zz, 0, 0, 0);
            zz = __builtin_amdgcn_mfma_f32_16x16x32_bf16(aq1, b1, zz, 0, 0, 0);
            sa[nt] = zz;
        }

        // ---- tail-tile key validity only ----
        if (kt == ktiles - 1 && (cntb & 63)) {
            #pragma unroll
            for (int nt = 0; nt < 4; ++nt) {
                bool bad = (k0 + nt * 16 + l15) >= cntb;
                #pragma unroll
                for (int r = 0; r < 4; ++r)
                    if (bad) sa[nt][r] = -1e13f;
            }
        }

        // ---- online softmax ----
        f32x4 av;
        #pragma unroll
        for (int r = 0; r < 4; ++r) {
            float t = fmaxf(fmaxf(sa[0][r], sa[1][r]), fmaxf(sa[2][r], sa[3][r]));
            t = fmaxf(t, __shfl_xor(t, 1));
            t = fmaxf(t, __shfl_xor(t, 2));
            t = fmaxf(t, __shfl_xor(t, 4));
            t = fmaxf(t, __shfl_xor(t, 8));
            float mnew = fmaxf(mi[r], t);
            float mc = mnew * C;
            float alpha = exp2f(fmaf(mi[r], C, -mc));
            mi[r] = mnew;
            float rs = 0.f;
            #pragma unroll
            for (int nt = 0; nt < 4; ++nt) {
                float p = exp2f(fmaf(sa[nt][r], C, -mc));
                sa[nt][r] = p;
                rs += p;
            }
            rs += __shfl_xor(rs, 1);
            rs += __shfl_xor(rs, 2);
            rs += __shfl_xor(rs, 4);
            rs += __shfl_xor(rs, 8);
            li[r] = li[r] * alpha + rs;
            av[r] = alpha;
        }
        #pragma unroll
        for (int nt = 0; nt < 4; ++nt) oacc[nt] = oacc[nt] * av;

        // ---- P (fp32) -> wave-private LDS ----
        #pragma unroll
        for (int r = 0; r < 4; ++r) {
            int qrow = quad * 4 + r;
            #pragma unroll
            for (int nt = 0; nt < 4; ++nt)
                Ps[wv][qrow][nt * 16 + l15] = sa[nt][r];
        }

        // ---- read A-fragment rows, pk-convert to bf16 ----
        float4 p0 = *(const float4*)&Ps[wv][l15][quad * 8];
        float4 p1 = *(const float4*)&Ps[wv][l15][quad * 8 + 4];
        float4 p2 = *(const float4*)&Ps[wv][l15][32 + quad * 8];
        float4 p3 = *(const float4*)&Ps[wv][l15][32 + quad * 8 + 4];
        union U8 { unsigned int u[4]; bf16x8 v8; };
        U8 ap0, ap1;
        ap0.u[0] = cvtpk(p0.x, p0.y); ap0.u[1] = cvtpk(p0.z, p0.w);
        ap0.u[2] = cvtpk(p1.x, p1.y); ap0.u[3] = cvtpk(p1.z, p1.w);
        ap1.u[0] = cvtpk(p2.x, p2.y); ap1.u[1] = cvtpk(p2.z, p2.w);
        ap1.u[2] = cvtpk(p3.x, p3.y); ap1.u[3] = cvtpk(p3.z, p3.w);

        // ---- O += P V ----
        #pragma unroll
        for (int nt = 0; nt < 4; ++nt) {
            bf16x8 v0 = *(const bf16x8*)&Vs[0][nt * 16 + l15][quad * 8];
            bf16x8 v1 = *(const bf16x8*)&Vs[1][nt * 16 + l15][quad * 8];
            oacc[nt] = __builtin_amdgcn_mfma_f32_16x16x32_bf16(ap0.v8, v0, oacc[nt], 0, 0, 0);
            oacc[nt] = __builtin_amdgcn_mfma_f32_16x16x32_bf16(ap1.v8, v1, oacc[nt], 0, 0, 0);
        }
    }

    // epilogue: ao [B,S,HD] bf16; masked queries take vmean
    #pragma unroll
    for (int r = 0; r < 4; ++r) {
        float inv = (li[r] > 0.f) ? 1.0f / li[r] : 0.f;
        int srow = q0 + quad * 4 + r;
        #pragma unroll
        for (int nt = 0; nt < 4; ++nt) {
            int d = nt * 16 + l15;
            float val = qp[r] ? vmean[bh * Dd + d] : oacc[nt][r] * inv;
            ao[((size_t)b * Ss + srow) * HD + h * Dd + d] = f2bf(val);
        }
    }
}

// ---------------------------------------------------------------------------
// Kernel 6: output projection.  A = ao bf16 [M,HD], B = Wo^T bf16, out fp32.
// ---------------------------------------------------------------------------
__global__ __launch_bounds__(256) void gemm_out(
    const unsigned short* __restrict__ a_in, const unsigned short* __restrict__ Wt,
    const float* __restrict__ bo, float* __restrict__ out)
{
    const unsigned short* Wz = Wt + (size_t)3 * 262144;
    const int m0 = blockIdx.x * 128, n0 = blockIdx.y * 128;
    const int tid = threadIdx.x, lane = tid & 63, wv = tid >> 6;
    const int quad = lane >> 4, l15 = lane & 15;
    const int wm = (wv >> 1) * 64, wn = (wv & 1) * 64;

    __shared__ unsigned short As[128][32];
    __shared__ unsigned short Bs[128][32];

    f32x4 acc[4][4] = {};

    for (int k0 = 0; k0 < HD; k0 += 32) {
        #pragma unroll
        for (int l = 0; l < 2; ++l) {
            int ci = tid + l * 256;
            int r = ci >> 2, ch = (ci & 3) * 8;
            *(uint4*)&As[r][ch] = *(const uint4*)(a_in + (size_t)(m0 + r) * HD + k0 + ch);
            *(uint4*)&Bs[r][ch] = *(const uint4*)(Wz + (size_t)(n0 + r) * HD + k0 + ch);
        }
        __syncthreads();
        bf16x8 af[4], bfr[4];
        #pragma unroll
        for (int ms = 0; ms < 4; ++ms) af[ms] = *(const bf16x8*)&As[wm + ms * 16 + l15][quad * 8];
        #pragma unroll
        for (int ns = 0; ns < 4; ++ns) bfr[ns] = *(const bf16x8*)&Bs[wn + ns * 16 + l15][quad * 8];
        #pragma unroll
        for (int ms = 0; ms < 4; ++ms)
            #pragma unroll
            for (int ns = 0; ns < 4; ++ns)
                acc[ms][ns] = __builtin_amdgcn_mfma_f32_16x16x32_bf16(af[ms], bfr[ns], acc[ms][ns], 0, 0, 0);
        __syncthreads();
    }

    #pragma unroll
    for (int ns = 0; ns < 4; ++ns) {
        int col = n0 + wn + ns * 16 + l15;
        float bb = bo[col];
        #pragma unroll
        for (int ms = 0; ms < 4; ++ms) {
            #pragma unroll
            for (int r = 0; r < 4; ++r) {
                int m = m0 + wm + ms * 16 + quad * 4 + r;
                out[(size_t)m * Ee + col] = acc[ms][ns][r] + bb;
            }
        }
    }
}

extern "C" void kernel_launch(void* const* d_in, const int* in_sizes, int n_in,
                              void* d_out, int out_size, void* d_ws, size_t ws_size,
                              hipStream_t stream) {
    const float* x   = (const float*)d_in[0];
    const int*   pad = (const int*)  d_in[1];
    const float* Wq  = (const float*)d_in[2];
    const float* bq  = (const float*)d_in[3];
    const float* Wk  = (const float*)d_in[4];
    const float* bk  = (const float*)d_in[5];
    const float* Wv  = (const float*)d_in[6];
    const float* bv  = (const float*)d_in[7];
    const float* Wo  = (const float*)d_in[8];
    const float* bo  = (const float*)d_in[9];
    float* out = (float*)d_out;

    const size_t tsz = (size_t)Bb * Hh * Ss * Dd;       // 4,194,304 elems
    unsigned short* Wt  = (unsigned short*)d_ws;        // 1,048,576 shorts
    unsigned short* qb  = Wt + 1048576;
    unsigned short* kb  = qb + tsz;
    unsigned short* vb  = kb + tsz;
    unsigned short* kc  = vb + tsz;
    unsigned short* vtc = kc + tsz;
    unsigned short* aob = kb;                           // kb dead after compact
    int* idxw   = (int*)(vtc + tsz);                    // 4*2048 ints
    int* cntw   = idxw + Bb * Ss;                       // 4 ints
    float* vmw  = (float*)(cntw + 4);                   // 32*64 floats

    dim3 g0(8, 8, 4);
    wconv<<<g0, 256, 0, stream>>>(Wq, Wk, Wv, Wo, Wt);

    dim3 g1(Mm / 128, HD / 128, 3);
    gemm_qkv<<<g1, 256, 0, stream>>>(x, Wt, bq, bk, bv, qb, kb, vb);

    scan_pad<<<Bb, 256, 0, stream>>>(pad, idxw, cntw);
    vmeank<<<Bb * Hh, 256, 0, stream>>>(vb, vmw);

    dim3 g2(Ss / 64, Bb * Hh);
    compact<<<g2, 256, 0, stream>>>(kb, vb, idxw, cntw, kc, vtc);

    dim3 g3(Ss / 64, Bb * Hh);
    attn<<<g3, 256, 0, stream>>>(qb, kc, vtc, pad, cntw, vmw, aob);

    dim3 g4(Mm / 128, Ee / 128);
    gemm_out<<<g4, 256, 0, stream>>>(aob, Wt, bo, out);
}

// Round 5
// 185.099 us; speedup vs baseline: 4.4715x; 1.1748x over previous
//
#include <hip/hip_runtime.h>
#include <hip/hip_bf16.h>
#include <math.h>

#define Bb 4
#define Ss 2048
#define Ee 512
#define Hh 8
#define Dd 64
#define HD 512
#define Mm (Bb*Ss)

using bf16x8 = __attribute__((ext_vector_type(8))) short;
using f32x4  = __attribute__((ext_vector_type(4))) float;

typedef __attribute__((address_space(1))) const unsigned int gu32;
typedef __attribute__((address_space(3))) unsigned int lu32;
__device__ inline void glds16(const void* g, void* l) {
    __builtin_amdgcn_global_load_lds((gu32*)g, (lu32*)l, 16, 0, 0);
}

__device__ inline unsigned short f2bf(float f) {
    unsigned int u = __float_as_uint(f);
    unsigned int r = (u + 0x7fffu + ((u >> 16) & 1u)) >> 16;
    return (unsigned short)r;
}
__device__ inline float bf2f(unsigned short u) {
    return __uint_as_float((unsigned int)u << 16);
}
__device__ inline unsigned int cvtpk(float a, float b) {
    float2 t; t.x = a; t.y = b;
    union { __hip_bfloat162 h; unsigned int u; } z;
    z.h = __float22bfloat162_rn(t);
    return z.u;
}

// ---------------------------------------------------------------------------
// Kernel 1: prep = wconv (256 blocks) + pad-scan (4) + x->bf16 (2048).
// ---------------------------------------------------------------------------
__global__ __launch_bounds__(256) void prep(
    const float* __restrict__ x, const int* __restrict__ pad,
    const float* __restrict__ Wq, const float* __restrict__ Wk,
    const float* __restrict__ Wv, const float* __restrict__ Wo,
    unsigned short* __restrict__ Wt, unsigned short* __restrict__ xb,
    int* __restrict__ idx, int* __restrict__ cnt)
{
    __shared__ float T[64][68];
    const int bi = blockIdx.x, tid = threadIdx.x;

    if (bi < 256) {
        // ---- weight convert+transpose: Wt[w][n][k] = bf16(W[w][k][n]) ----
        const int w = bi >> 6;
        const float* W = (w == 0) ? Wq : (w == 1) ? Wk : (w == 2) ? Wv : Wo;
        const int tk0 = ((bi >> 3) & 7) * 64, tn0 = (bi & 7) * 64;
        #pragma unroll
        for (int l = 0; l < 4; ++l) {
            int fi = tid + l * 256;
            int r = fi >> 4, c4 = (fi & 15) * 4;
            *(float4*)&T[r][c4] = *(const float4*)(W + (size_t)(tk0 + r) * Ee + tn0 + c4);
        }
        __syncthreads();
        #pragma unroll
        for (int l = 0; l < 4; ++l) {
            int fi = tid + l * 256;
            int r2 = fi >> 4, c4 = (fi & 15) * 4;
            uint2 o;
            o.x = cvtpk(T[c4 + 0][r2], T[c4 + 1][r2]);
            o.y = cvtpk(T[c4 + 2][r2], T[c4 + 3][r2]);
            *(uint2*)(Wt + (size_t)w * 262144 + (size_t)(tn0 + r2) * Ee + tk0 + c4) = o;
        }
    } else if (bi < 260) {
        // ---- per-batch compaction scan ----
        const int b = bi - 256;
        int* sc = (int*)&T[0][0];
        int loc[8], c = 0;
        #pragma unroll
        for (int j = 0; j < 8; ++j) {
            loc[j] = pad[b * Ss + tid * 8 + j];
            c += (loc[j] == 0);
        }
        sc[tid] = c;
        __syncthreads();
        for (int s = 1; s < 256; s <<= 1) {
            int v = (tid >= s) ? sc[tid - s] : 0;
            __syncthreads();
            sc[tid] += v;
            __syncthreads();
        }
        int off = b * Ss + sc[tid] - c;
        #pragma unroll
        for (int j = 0; j < 8; ++j)
            if (loc[j] == 0) idx[off++] = tid * 8 + j;
        if (tid == 255) cnt[b] = sc[255];
    } else {
        // ---- x (fp32) -> xb (bf16), 2048 elems per block ----
        const size_t off = (size_t)(bi - 260) * 2048 + tid * 8;
        float4 a = *(const float4*)(x + off);
        float4 bfl = *(const float4*)(x + off + 4);
        uint4 o;
        o.x = cvtpk(a.x, a.y); o.y = cvtpk(a.z, a.w);
        o.z = cvtpk(bfl.x, bfl.y); o.w = cvtpk(bfl.z, bfl.w);
        *(uint4*)(xb + off) = o;
    }
}

// ---------------------------------------------------------------------------
// Kernel 2: QKV projection, bf16 MFMA, global_load_lds staging.
// q pre-scaled by 0.125*log2(e) (folds softmax scale + exp2 base change).
// ---------------------------------------------------------------------------
__global__ __launch_bounds__(256) void gemm_qkv(
    const unsigned short* __restrict__ xb, const unsigned short* __restrict__ Wt,
    const float* __restrict__ bq, const float* __restrict__ bk, const float* __restrict__ bv,
    unsigned short* __restrict__ qo, unsigned short* __restrict__ ko, unsigned short* __restrict__ vo)
{
    const int z = blockIdx.z;
    const unsigned short* Wz = Wt + (size_t)z * 262144;
    const float* bias = (z == 0) ? bq : (z == 1) ? bk : bv;
    unsigned short* dst = (z == 0) ? qo : (z == 1) ? ko : vo;

    const int m0 = blockIdx.x * 128, n0 = blockIdx.y * 128;
    const int tid = threadIdx.x, lane = tid & 63, wv = tid >> 6;
    const int quad = lane >> 4, l15 = lane & 15;
    const int wm = (wv >> 1) * 64, wn = (wv & 1) * 64;

    __shared__ unsigned short As[128][32];
    __shared__ unsigned short Bs[128][32];

    f32x4 acc[4][4] = {};

    for (int k0 = 0; k0 < Ee; k0 += 32) {
        #pragma unroll
        for (int l = 0; l < 2; ++l) {
            int ci = tid + l * 256;
            int r = ci >> 2, ch = (ci & 3) * 8;
            glds16(xb + (size_t)(m0 + r) * Ee + k0 + ch, &As[r][ch]);
            glds16(Wz + (size_t)(n0 + r) * Ee + k0 + ch, &Bs[r][ch]);
        }
        __syncthreads();

        bf16x8 af[4], bfr[4];
        #pragma unroll
        for (int ms = 0; ms < 4; ++ms) af[ms] = *(const bf16x8*)&As[wm + ms * 16 + l15][quad * 8];
        #pragma unroll
        for (int ns = 0; ns < 4; ++ns) bfr[ns] = *(const bf16x8*)&Bs[wn + ns * 16 + l15][quad * 8];
        #pragma unroll
        for (int ms = 0; ms < 4; ++ms)
            #pragma unroll
            for (int ns = 0; ns < 4; ++ns)
                acc[ms][ns] = __builtin_amdgcn_mfma_f32_16x16x32_bf16(af[ms], bfr[ns], acc[ms][ns], 0, 0, 0);
        __syncthreads();
    }

    #pragma unroll
    for (int ns = 0; ns < 4; ++ns) {
        int col = n0 + wn + ns * 16 + l15;
        float bb = bias[col];
        int h = col >> 6, d = col & 63;
        #pragma unroll
        for (int ms = 0; ms < 4; ++ms) {
            #pragma unroll
            for (int r = 0; r < 4; ++r) {
                int m = m0 + wm + ms * 16 + quad * 4 + r;
                int b = m >> 11, s = m & 2047;
                float val = acc[ms][ns][r] + bb;
                if (z == 0) val *= 0.18033688f;   // 0.125 * log2(e)
                dst[((size_t)(b * Hh + h) * Ss + s) * Dd + d] = f2bf(val);
            }
        }
    }
}

// ---------------------------------------------------------------------------
// Kernel 3: compact K/V^T (bx<32) + vmean (bx==32).
// ---------------------------------------------------------------------------
__global__ __launch_bounds__(256) void compact_vmean(
    const unsigned short* __restrict__ kb, const unsigned short* __restrict__ vb,
    const int* __restrict__ idx, const int* __restrict__ cnt,
    unsigned short* __restrict__ kc, unsigned short* __restrict__ vtc,
    float* __restrict__ vmean)
{
    const int bh = blockIdx.y, b = bh >> 3;
    const int bx = blockIdx.x, tid = threadIdx.x;

    if (bx == 32) {
        // ---- vmean[bh][d] = mean over ALL s of v ----
        __shared__ float sm[32][64];
        const int chunk = tid & 7, part = tid >> 3;
        float a8[8] = {};
        const unsigned short* p = vb + (size_t)bh * Ss * Dd + chunk * 8;
        for (int i = 0; i < 64; ++i) {
            union { unsigned short u[8]; uint4 q; } t;
            t.q = *(const uint4*)(p + (size_t)(part * 64 + i) * Dd);
            #pragma unroll
            for (int j = 0; j < 8; ++j) a8[j] += bf2f(t.u[j]);
        }
        #pragma unroll
        for (int j = 0; j < 8; ++j) sm[part][chunk * 8 + j] = a8[j];
        __syncthreads();
        if (tid < 64) {
            float s = 0.f;
            #pragma unroll 8
            for (int pp = 0; pp < 32; ++pp) s += sm[pp][tid];
            vmean[bh * Dd + tid] = s * (1.0f / 2048.0f);
        }
        return;
    }

    const int cntb = cnt[b];
    const int j0 = bx * 64;
    if (j0 >= cntb) return;
    const unsigned short* kbb = kb + (size_t)bh * Ss * Dd;
    const unsigned short* vbb = vb + (size_t)bh * Ss * Dd;
    __shared__ unsigned short T[64][72];
    __shared__ int sidx[64];
    if (tid < 64) {
        int j = j0 + tid;
        sidx[tid] = (j < cntb) ? idx[b * Ss + j] : -1;
    }
    __syncthreads();
    #pragma unroll
    for (int l = 0; l < 2; ++l) {
        int ci = tid + l * 256;
        int r = ci >> 3, ch = (ci & 7) * 8;
        int s = sidx[r];
        uint4 kd = {0, 0, 0, 0}, vd = {0, 0, 0, 0};
        if (s >= 0) {
            kd = *(const uint4*)(kbb + (size_t)s * Dd + ch);
            vd = *(const uint4*)(vbb + (size_t)s * Dd + ch);
        }
        *(uint4*)(kc + ((size_t)bh * Ss + j0 + r) * Dd + ch) = kd;
        *(uint4*)&T[r][ch] = vd;
    }
    __syncthreads();
    #pragma unroll
    for (int l = 0; l < 2; ++l) {
        int ci = tid + l * 256;
        int dr = ci >> 3, sc8 = (ci & 7) * 8;
        union { unsigned short u[8]; uint4 q; } o;
        #pragma unroll
        for (int j = 0; j < 8; ++j) o.u[j] = T[sc8 + j][dr];
        *(uint4*)(vtc + ((size_t)bh * Dd + dr) * Ss + j0 + sc8) = o.q;
    }
}

// ---------------------------------------------------------------------------
// Kernel 4: flash attention v2.  4 waves x 32 q-rows = 128 q per block.
// Exp-only softmax (no max subtraction: scores pre-scaled into log2 domain,
// |s'| < 1 so exp2 is exact-safe; masked keys are compacted away).
// Per-lane l accumulation; single shuffle tree at epilogue.
// ---------------------------------------------------------------------------
__global__ __launch_bounds__(256) void attn(
    const unsigned short* __restrict__ q, const unsigned short* __restrict__ kc,
    const unsigned short* __restrict__ vtc, const int* __restrict__ pad,
    const int* __restrict__ cnt, const float* __restrict__ vmean,
    unsigned short* __restrict__ ao)
{
    __shared__ unsigned short Ks[2][64][32];
    __shared__ unsigned short Vs[2][64][32];
    __shared__ float Ps[4][16][68];

    const int tid = threadIdx.x, wv = tid >> 6, lane = tid & 63;
    const int quad = lane >> 4, l15 = lane & 15;
    const int bh = blockIdx.y, b = bh >> 3, h = bh & 7;
    const int q0 = blockIdx.x * 128 + wv * 32;

    const unsigned short* qb  = q   + (size_t)bh * Ss * Dd;
    const unsigned short* kcb = kc  + (size_t)bh * Ss * Dd;
    const unsigned short* vtb = vtc + (size_t)bh * Dd * Ss;

    const int cntb = cnt[b];
    const int ktiles = (cntb + 63) >> 6;
    const bool tail = (cntb & 63) != 0;

    bf16x8 aq[2][2];
    #pragma unroll
    for (int g = 0; g < 2; ++g) {
        aq[g][0] = *(const bf16x8*)(qb + (size_t)(q0 + g * 16 + l15) * Dd + quad * 8);
        aq[g][1] = *(const bf16x8*)(qb + (size_t)(q0 + g * 16 + l15) * Dd + 32 + quad * 8);
    }

    bool qp[2][4];
    #pragma unroll
    for (int g = 0; g < 2; ++g)
        #pragma unroll
        for (int r = 0; r < 4; ++r)
            qp[g][r] = pad[b * Ss + q0 + g * 16 + quad * 4 + r] != 0;

    float li[2][4] = {};
    f32x4 oacc[2][4] = {};

    for (int kt = 0; kt < ktiles; ++kt) {
        const int k0 = kt * 64;
        __syncthreads();
        #pragma unroll
        for (int l = 0; l < 2; ++l) {
            int ci = tid + l * 256;
            int s = ci >> 8, row = (ci >> 2) & 63, ch = (ci & 3) * 8;
            glds16(kcb + (size_t)(k0 + row) * Dd + s * 32 + ch, &Ks[s][row][ch]);
            glds16(vtb + (size_t)row * Ss + k0 + s * 32 + ch, &Vs[s][row][ch]);
        }
        __syncthreads();

        // cache K/V fragments in registers (shared across both row-groups)
        bf16x8 kf[4][2], vf[4][2];
        #pragma unroll
        for (int nt = 0; nt < 4; ++nt) {
            kf[nt][0] = *(const bf16x8*)&Ks[0][nt * 16 + l15][quad * 8];
            kf[nt][1] = *(const bf16x8*)&Ks[1][nt * 16 + l15][quad * 8];
            vf[nt][0] = *(const bf16x8*)&Vs[0][nt * 16 + l15][quad * 8];
            vf[nt][1] = *(const bf16x8*)&Vs[1][nt * 16 + l15][quad * 8];
        }

        #pragma unroll
        for (int g = 0; g < 2; ++g) {
            // ---- S' = Q' K^T (already in log2 domain) ----
            f32x4 sa[4];
            #pragma unroll
            for (int nt = 0; nt < 4; ++nt) {
                f32x4 zz = {0.f, 0.f, 0.f, 0.f};
                zz = __builtin_amdgcn_mfma_f32_16x16x32_bf16(aq[g][0], kf[nt][0], zz, 0, 0, 0);
                zz = __builtin_amdgcn_mfma_f32_16x16x32_bf16(aq[g][1], kf[nt][1], zz, 0, 0, 0);
                sa[nt] = zz;
            }

            if (tail && kt == ktiles - 1) {
                #pragma unroll
                for (int nt = 0; nt < 4; ++nt) {
                    bool bad = (k0 + nt * 16 + l15) >= cntb;
                    #pragma unroll
                    for (int r = 0; r < 4; ++r)
                        if (bad) sa[nt][r] = -1e30f;
                }
            }

            // ---- p = exp2(s'), accumulate l per lane ----
            #pragma unroll
            for (int nt = 0; nt < 4; ++nt)
                #pragma unroll
                for (int r = 0; r < 4; ++r) {
                    float p = exp2f(sa[nt][r]);
                    sa[nt][r] = p;
                    li[g][r] += p;
                }

            // ---- P (fp32) -> wave-private LDS, read back as A-fragments ----
            #pragma unroll
            for (int r = 0; r < 4; ++r) {
                int qrow = quad * 4 + r;
                #pragma unroll
                for (int nt = 0; nt < 4; ++nt)
                    Ps[wv][qrow][nt * 16 + l15] = sa[nt][r];
            }
            float4 p0 = *(const float4*)&Ps[wv][l15][quad * 8];
            float4 p1 = *(const float4*)&Ps[wv][l15][quad * 8 + 4];
            float4 p2 = *(const float4*)&Ps[wv][l15][32 + quad * 8];
            float4 p3 = *(const float4*)&Ps[wv][l15][32 + quad * 8 + 4];
            union U8 { unsigned int u[4]; bf16x8 v8; };
            U8 ap0, ap1;
            ap0.u[0] = cvtpk(p0.x, p0.y); ap0.u[1] = cvtpk(p0.z, p0.w);
            ap0.u[2] = cvtpk(p1.x, p1.y); ap0.u[3] = cvtpk(p1.z, p1.w);
            ap1.u[0] = cvtpk(p2.x, p2.y); ap1.u[1] = cvtpk(p2.z, p2.w);
            ap1.u[2] = cvtpk(p3.x, p3.y); ap1.u[3] = cvtpk(p3.z, p3.w);

            // ---- O += P V ----
            #pragma unroll
            for (int nt = 0; nt < 4; ++nt) {
                oacc[g][nt] = __builtin_amdgcn_mfma_f32_16x16x32_bf16(ap0.v8, vf[nt][0], oacc[g][nt], 0, 0, 0);
                oacc[g][nt] = __builtin_amdgcn_mfma_f32_16x16x32_bf16(ap1.v8, vf[nt][1], oacc[g][nt], 0, 0, 0);
            }
        }
    }

    // ---- epilogue: one l-reduction tree, store ao [B,S,HD] bf16 ----
    #pragma unroll
    for (int g = 0; g < 2; ++g) {
        #pragma unroll
        for (int r = 0; r < 4; ++r) {
            float ls = li[g][r];
            ls += __shfl_xor(ls, 1);
            ls += __shfl_xor(ls, 2);
            ls += __shfl_xor(ls, 4);
            ls += __shfl_xor(ls, 8);
            float inv = (ls > 0.f) ? 1.0f / ls : 0.f;
            int srow = q0 + g * 16 + quad * 4 + r;
            #pragma unroll
            for (int nt = 0; nt < 4; ++nt) {
                int d = nt * 16 + l15;
                float val = qp[g][r] ? vmean[bh * Dd + d] : oacc[g][nt][r] * inv;
                ao[((size_t)b * Ss + srow) * HD + h * Dd + d] = f2bf(val);
            }
        }
    }
}

// ---------------------------------------------------------------------------
// Kernel 5: output projection, global_load_lds staging.
// ---------------------------------------------------------------------------
__global__ __launch_bounds__(256) void gemm_out(
    const unsigned short* __restrict__ a_in, const unsigned short* __restrict__ Wt,
    const float* __restrict__ bo, float* __restrict__ out)
{
    const unsigned short* Wz = Wt + (size_t)3 * 262144;
    const int m0 = blockIdx.x * 128, n0 = blockIdx.y * 128;
    const int tid = threadIdx.x, lane = tid & 63, wv = tid >> 6;
    const int quad = lane >> 4, l15 = lane & 15;
    const int wm = (wv >> 1) * 64, wn = (wv & 1) * 64;

    __shared__ unsigned short As[128][32];
    __shared__ unsigned short Bs[128][32];

    f32x4 acc[4][4] = {};

    for (int k0 = 0; k0 < HD; k0 += 32) {
        #pragma unroll
        for (int l = 0; l < 2; ++l) {
            int ci = tid + l * 256;
            int r = ci >> 2, ch = (ci & 3) * 8;
            glds16(a_in + (size_t)(m0 + r) * HD + k0 + ch, &As[r][ch]);
            glds16(Wz + (size_t)(n0 + r) * HD + k0 + ch, &Bs[r][ch]);
        }
        __syncthreads();
        bf16x8 af[4], bfr[4];
        #pragma unroll
        for (int ms = 0; ms < 4; ++ms) af[ms] = *(const bf16x8*)&As[wm + ms * 16 + l15][quad * 8];
        #pragma unroll
        for (int ns = 0; ns < 4; ++ns) bfr[ns] = *(const bf16x8*)&Bs[wn + ns * 16 + l15][quad * 8];
        #pragma unroll
        for (int ms = 0; ms < 4; ++ms)
            #pragma unroll
            for (int ns = 0; ns < 4; ++ns)
                acc[ms][ns] = __builtin_amdgcn_mfma_f32_16x16x32_bf16(af[ms], bfr[ns], acc[ms][ns], 0, 0, 0);
        __syncthreads();
    }

    #pragma unroll
    for (int ns = 0; ns < 4; ++ns) {
        int col = n0 + wn + ns * 16 + l15;
        float bb = bo[col];
        #pragma unroll
        for (int ms = 0; ms < 4; ++ms) {
            #pragma unroll
            for (int r = 0; r < 4; ++r) {
                int m = m0 + wm + ms * 16 + quad * 4 + r;
                out[(size_t)m * Ee + col] = acc[ms][ns][r] + bb;
            }
        }
    }
}

extern "C" void kernel_launch(void* const* d_in, const int* in_sizes, int n_in,
                              void* d_out, int out_size, void* d_ws, size_t ws_size,
                              hipStream_t stream) {
    const float* x   = (const float*)d_in[0];
    const int*   pad = (const int*)  d_in[1];
    const float* Wq  = (const float*)d_in[2];
    const float* bq  = (const float*)d_in[3];
    const float* Wk  = (const float*)d_in[4];
    const float* bk  = (const float*)d_in[5];
    const float* Wv  = (const float*)d_in[6];
    const float* bv  = (const float*)d_in[7];
    const float* Wo  = (const float*)d_in[8];
    const float* bo  = (const float*)d_in[9];
    float* out = (float*)d_out;

    const size_t tsz = (size_t)Bb * Hh * Ss * Dd;       // 4,194,304 elems
    unsigned short* Wt  = (unsigned short*)d_ws;        // 1,048,576 shorts
    unsigned short* qb  = Wt + 1048576;
    unsigned short* kb  = qb + tsz;
    unsigned short* vb  = kb + tsz;
    unsigned short* kc  = vb + tsz;
    unsigned short* xb  = kc + tsz;                     // aliased: vtc after gemm_qkv
    unsigned short* vtc = xb;                           // xb dead once gemm_qkv done
    unsigned short* aob = kb;                           // kb dead after compact
    int* idxw   = (int*)(xb + tsz);
    int* cntw   = idxw + Bb * Ss;
    float* vmw  = (float*)(cntw + 4);

    prep<<<2308, 256, 0, stream>>>(x, pad, Wq, Wk, Wv, Wo, Wt, xb, idxw, cntw);

    dim3 g1(Mm / 128, HD / 128, 3);
    gemm_qkv<<<g1, 256, 0, stream>>>(xb, Wt, bq, bk, bv, qb, kb, vb);

    dim3 g2(33, Bb * Hh);
    compact_vmean<<<g2, 256, 0, stream>>>(kb, vb, idxw, cntw, kc, vtc, vmw);

    dim3 g3(Ss / 128, Bb * Hh);
    attn<<<g3, 256, 0, stream>>>(qb, kc, vtc, pad, cntw, vmw, aob);

    dim3 g4(Mm / 128, Ee / 128);
    gemm_out<<<g4, 256, 0, stream>>>(aob, Wt, bo, out);
}

// Round 6
// 173.002 us; speedup vs baseline: 4.7842x; 1.0699x over previous
//
#include <hip/hip_runtime.h>
#include <hip/hip_bf16.h>
#include <math.h>

#define Bb 4
#define Ss 2048
#define Ee 512
#define Hh 8
#define Dd 64
#define HD 512
#define Mm (Bb*Ss)

using bf16x8 = __attribute__((ext_vector_type(8))) short;
using f32x4  = __attribute__((ext_vector_type(4))) float;

typedef __attribute__((address_space(1))) const unsigned int gu32;
typedef __attribute__((address_space(3))) unsigned int lu32;
__device__ inline void glds16(const void* g, void* l) {
    __builtin_amdgcn_global_load_lds((gu32*)g, (lu32*)l, 16, 0, 0);
}

__device__ inline unsigned short f2bf(float f) {
    unsigned int u = __float_as_uint(f);
    unsigned int r = (u + 0x7fffu + ((u >> 16) & 1u)) >> 16;
    return (unsigned short)r;
}
__device__ inline float bf2f(unsigned short u) {
    return __uint_as_float((unsigned int)u << 16);
}
__device__ inline unsigned int cvtpk(float a, float b) {
    float2 t; t.x = a; t.y = b;
    union { __hip_bfloat162 h; unsigned int u; } z;
    z.h = __float22bfloat162_rn(t);
    return z.u;
}

// ---------------------------------------------------------------------------
// Kernel 1: prep = wconv (256 blocks) + pad-scan (4) + x->bf16 (2048).
// ---------------------------------------------------------------------------
__global__ __launch_bounds__(256) void prep(
    const float* __restrict__ x, const int* __restrict__ pad,
    const float* __restrict__ Wq, const float* __restrict__ Wk,
    const float* __restrict__ Wv, const float* __restrict__ Wo,
    unsigned short* __restrict__ Wt, unsigned short* __restrict__ xb,
    int* __restrict__ idx, int* __restrict__ cnt)
{
    __shared__ float T[64][68];
    const int bi = blockIdx.x, tid = threadIdx.x;

    if (bi < 256) {
        const int w = bi >> 6;
        const float* W = (w == 0) ? Wq : (w == 1) ? Wk : (w == 2) ? Wv : Wo;
        const int tk0 = ((bi >> 3) & 7) * 64, tn0 = (bi & 7) * 64;
        #pragma unroll
        for (int l = 0; l < 4; ++l) {
            int fi = tid + l * 256;
            int r = fi >> 4, c4 = (fi & 15) * 4;
            *(float4*)&T[r][c4] = *(const float4*)(W + (size_t)(tk0 + r) * Ee + tn0 + c4);
        }
        __syncthreads();
        #pragma unroll
        for (int l = 0; l < 4; ++l) {
            int fi = tid + l * 256;
            int r2 = fi >> 4, c4 = (fi & 15) * 4;
            uint2 o;
            o.x = cvtpk(T[c4 + 0][r2], T[c4 + 1][r2]);
            o.y = cvtpk(T[c4 + 2][r2], T[c4 + 3][r2]);
            *(uint2*)(Wt + (size_t)w * 262144 + (size_t)(tn0 + r2) * Ee + tk0 + c4) = o;
        }
    } else if (bi < 260) {
        const int b = bi - 256;
        int* sc = (int*)&T[0][0];
        int loc[8], c = 0;
        #pragma unroll
        for (int j = 0; j < 8; ++j) {
            loc[j] = pad[b * Ss + tid * 8 + j];
            c += (loc[j] == 0);
        }
        sc[tid] = c;
        __syncthreads();
        for (int s = 1; s < 256; s <<= 1) {
            int v = (tid >= s) ? sc[tid - s] : 0;
            __syncthreads();
            sc[tid] += v;
            __syncthreads();
        }
        int off = b * Ss + sc[tid] - c;
        #pragma unroll
        for (int j = 0; j < 8; ++j)
            if (loc[j] == 0) idx[off++] = tid * 8 + j;
        if (tid == 255) cnt[b] = sc[255];
    } else {
        const size_t off = (size_t)(bi - 260) * 2048 + tid * 8;
        float4 a = *(const float4*)(x + off);
        float4 bfl = *(const float4*)(x + off + 4);
        uint4 o;
        o.x = cvtpk(a.x, a.y); o.y = cvtpk(a.z, a.w);
        o.z = cvtpk(bfl.x, bfl.y); o.w = cvtpk(bfl.z, bfl.w);
        *(uint4*)(xb + off) = o;
    }
}

// ---------------------------------------------------------------------------
// Kernel 2: QKV projection, bf16 MFMA, double-buffered glds staging.
// Outputs q/k/v bf16 in NATURAL [M, 512] layout (coalesced epilogue).
// q pre-scaled by 0.125*log2(e).
// ---------------------------------------------------------------------------
__global__ __launch_bounds__(256) void gemm_qkv(
    const unsigned short* __restrict__ xb, const unsigned short* __restrict__ Wt,
    const float* __restrict__ bq, const float* __restrict__ bk, const float* __restrict__ bv,
    unsigned short* __restrict__ qo, unsigned short* __restrict__ ko, unsigned short* __restrict__ vo)
{
    const int z = blockIdx.z;
    const unsigned short* Wz = Wt + (size_t)z * 262144;
    const float* bias = (z == 0) ? bq : (z == 1) ? bk : bv;
    unsigned short* dst = (z == 0) ? qo : (z == 1) ? ko : vo;

    const int m0 = blockIdx.x * 128, n0 = blockIdx.y * 128;
    const int tid = threadIdx.x, lane = tid & 63, wv = tid >> 6;
    const int quad = lane >> 4, l15 = lane & 15;
    const int wm = (wv >> 1) * 64, wn = (wv & 1) * 64;

    __shared__ unsigned short As0[128][32], Bs0[128][32];
    __shared__ unsigned short As1[128][32], Bs1[128][32];

    f32x4 acc[4][4] = {};

    auto stage = [&](unsigned short (&A)[128][32], unsigned short (&B)[128][32], int k0) {
        #pragma unroll
        for (int l = 0; l < 2; ++l) {
            int ci = tid + l * 256;
            int r = ci >> 2, ch = (ci & 3) * 8;
            glds16(xb + (size_t)(m0 + r) * Ee + k0 + ch, &A[r][ch]);
            glds16(Wz + (size_t)(n0 + r) * Ee + k0 + ch, &B[r][ch]);
        }
    };
    auto compute = [&](const unsigned short (&A)[128][32], const unsigned short (&B)[128][32]) {
        bf16x8 af[4], bfr[4];
        #pragma unroll
        for (int ms = 0; ms < 4; ++ms) af[ms] = *(const bf16x8*)&A[wm + ms * 16 + l15][quad * 8];
        #pragma unroll
        for (int ns = 0; ns < 4; ++ns) bfr[ns] = *(const bf16x8*)&B[wn + ns * 16 + l15][quad * 8];
        #pragma unroll
        for (int ms = 0; ms < 4; ++ms)
            #pragma unroll
            for (int ns = 0; ns < 4; ++ns)
                acc[ms][ns] = __builtin_amdgcn_mfma_f32_16x16x32_bf16(af[ms], bfr[ns], acc[ms][ns], 0, 0, 0);
    };

    stage(As0, Bs0, 0);
    for (int ki = 0; ki < 16; ki += 2) {
        __syncthreads();
        if (ki + 1 < 16) stage(As1, Bs1, (ki + 1) * 32);
        compute(As0, Bs0);
        __syncthreads();
        if (ki + 2 < 16) stage(As0, Bs0, (ki + 2) * 32);
        compute(As1, Bs1);
    }

    #pragma unroll
    for (int ns = 0; ns < 4; ++ns) {
        int col = n0 + wn + ns * 16 + l15;
        float bb = bias[col];
        #pragma unroll
        for (int ms = 0; ms < 4; ++ms) {
            #pragma unroll
            for (int r = 0; r < 4; ++r) {
                int m = m0 + wm + ms * 16 + quad * 4 + r;
                float val = acc[ms][ns][r] + bb;
                if (z == 0) val *= 0.18033688f;   // 0.125 * log2(e)
                dst[(size_t)m * HD + col] = f2bf(val);
            }
        }
    }
}

// ---------------------------------------------------------------------------
// Kernel 3: compact K/V^T (bx<32) + vmean (bx==32).  Inputs now [M, 512].
// ---------------------------------------------------------------------------
__global__ __launch_bounds__(256) void compact_vmean(
    const unsigned short* __restrict__ kb, const unsigned short* __restrict__ vb,
    const int* __restrict__ idx, const int* __restrict__ cnt,
    unsigned short* __restrict__ kc, unsigned short* __restrict__ vtc,
    float* __restrict__ vmean)
{
    const int bh = blockIdx.y, b = bh >> 3, h = bh & 7;
    const int bx = blockIdx.x, tid = threadIdx.x;

    if (bx == 32) {
        __shared__ float sm[32][64];
        const int chunk = tid & 7, part = tid >> 3;
        float a8[8] = {};
        const unsigned short* p = vb + (size_t)b * Ss * HD + h * Dd + chunk * 8;
        for (int i = 0; i < 64; ++i) {
            union { unsigned short u[8]; uint4 q; } t;
            t.q = *(const uint4*)(p + (size_t)(part * 64 + i) * HD);
            #pragma unroll
            for (int j = 0; j < 8; ++j) a8[j] += bf2f(t.u[j]);
        }
        #pragma unroll
        for (int j = 0; j < 8; ++j) sm[part][chunk * 8 + j] = a8[j];
        __syncthreads();
        if (tid < 64) {
            float s = 0.f;
            #pragma unroll 8
            for (int pp = 0; pp < 32; ++pp) s += sm[pp][tid];
            vmean[bh * Dd + tid] = s * (1.0f / 2048.0f);
        }
        return;
    }

    const int cntb = cnt[b];
    const int j0 = bx * 64;
    if (j0 >= cntb) return;
    __shared__ unsigned short T[64][72];
    __shared__ int sidx[64];
    if (tid < 64) {
        int j = j0 + tid;
        sidx[tid] = (j < cntb) ? idx[b * Ss + j] : -1;
    }
    __syncthreads();
    #pragma unroll
    for (int l = 0; l < 2; ++l) {
        int ci = tid + l * 256;
        int r = ci >> 3, ch = (ci & 7) * 8;
        int s = sidx[r];
        uint4 kd = {0, 0, 0, 0}, vd = {0, 0, 0, 0};
        if (s >= 0) {
            size_t row = (size_t)(b * Ss + s) * HD + h * Dd;
            kd = *(const uint4*)(kb + row + ch);
            vd = *(const uint4*)(vb + row + ch);
        }
        *(uint4*)(kc + ((size_t)bh * Ss + j0 + r) * Dd + ch) = kd;
        *(uint4*)&T[r][ch] = vd;
    }
    __syncthreads();
    #pragma unroll
    for (int l = 0; l < 2; ++l) {
        int ci = tid + l * 256;
        int dr = ci >> 3, sc8 = (ci & 7) * 8;
        union { unsigned short u[8]; uint4 q; } o;
        #pragma unroll
        for (int j = 0; j < 8; ++j) o.u[j] = T[sc8 + j][dr];
        *(uint4*)(vtc + ((size_t)bh * Dd + dr) * Ss + j0 + sc8) = o.q;
    }
}

// ---------------------------------------------------------------------------
// Kernel 4: flash attention v3.  4 waves x 32 q-rows = 128 q per block.
// Double-buffered K/V staging (one barrier per tile, prefetch overlapped).
// Exp-only softmax; per-lane l; grid x=bh (mix batches across CUs).
// ---------------------------------------------------------------------------
__global__ __launch_bounds__(256) void attn(
    const unsigned short* __restrict__ q, const unsigned short* __restrict__ kc,
    const unsigned short* __restrict__ vtc, const int* __restrict__ pad,
    const int* __restrict__ cnt, const float* __restrict__ vmean,
    unsigned short* __restrict__ ao)
{
    __shared__ unsigned short Ks0[2][64][32], Vs0[2][64][32];
    __shared__ unsigned short Ks1[2][64][32], Vs1[2][64][32];
    __shared__ float Ps[4][16][68];

    const int tid = threadIdx.x, wv = tid >> 6, lane = tid & 63;
    const int quad = lane >> 4, l15 = lane & 15;
    const int bh = blockIdx.x, b = bh >> 3, h = bh & 7;
    const int q0 = blockIdx.y * 128 + wv * 32;

    const unsigned short* kcb = kc  + (size_t)bh * Ss * Dd;
    const unsigned short* vtb = vtc + (size_t)bh * Dd * Ss;

    const int cntb = cnt[b];
    const int ktiles = (cntb + 63) >> 6;
    const bool tail = (cntb & 63) != 0;

    bf16x8 aq[2][2];
    #pragma unroll
    for (int g = 0; g < 2; ++g) {
        size_t row = (size_t)(b * Ss + q0 + g * 16 + l15) * HD + h * Dd;
        aq[g][0] = *(const bf16x8*)(q + row + quad * 8);
        aq[g][1] = *(const bf16x8*)(q + row + 32 + quad * 8);
    }

    bool qp[2][4];
    #pragma unroll
    for (int g = 0; g < 2; ++g)
        #pragma unroll
        for (int r = 0; r < 4; ++r)
            qp[g][r] = pad[b * Ss + q0 + g * 16 + quad * 4 + r] != 0;

    float li[2][4] = {};
    f32x4 oacc[2][4] = {};

    auto stage = [&](unsigned short (&K)[2][64][32], unsigned short (&V)[2][64][32], int kt) {
        const int k0 = kt * 64;
        #pragma unroll
        for (int l = 0; l < 2; ++l) {
            int ci = tid + l * 256;
            int s = ci >> 8, row = (ci >> 2) & 63, ch = (ci & 3) * 8;
            glds16(kcb + (size_t)(k0 + row) * Dd + s * 32 + ch, &K[s][row][ch]);
            glds16(vtb + (size_t)row * Ss + k0 + s * 32 + ch, &V[s][row][ch]);
        }
    };

    auto compute = [&](const unsigned short (&K)[2][64][32], const unsigned short (&V)[2][64][32], int kt) {
        const int k0 = kt * 64;
        bf16x8 kf[4][2], vf[4][2];
        #pragma unroll
        for (int nt = 0; nt < 4; ++nt) {
            kf[nt][0] = *(const bf16x8*)&K[0][nt * 16 + l15][quad * 8];
            kf[nt][1] = *(const bf16x8*)&K[1][nt * 16 + l15][quad * 8];
            vf[nt][0] = *(const bf16x8*)&V[0][nt * 16 + l15][quad * 8];
            vf[nt][1] = *(const bf16x8*)&V[1][nt * 16 + l15][quad * 8];
        }
        #pragma unroll
        for (int g = 0; g < 2; ++g) {
            f32x4 sa[4];
            #pragma unroll
            for (int nt = 0; nt < 4; ++nt) {
                f32x4 zz = {0.f, 0.f, 0.f, 0.f};
                zz = __builtin_amdgcn_mfma_f32_16x16x32_bf16(aq[g][0], kf[nt][0], zz, 0, 0, 0);
                zz = __builtin_amdgcn_mfma_f32_16x16x32_bf16(aq[g][1], kf[nt][1], zz, 0, 0, 0);
                sa[nt] = zz;
            }
            if (tail && kt == ktiles - 1) {
                #pragma unroll
                for (int nt = 0; nt < 4; ++nt) {
                    bool bad = (k0 + nt * 16 + l15) >= cntb;
                    #pragma unroll
                    for (int r = 0; r < 4; ++r)
                        if (bad) sa[nt][r] = -1e30f;
                }
            }
            #pragma unroll
            for (int nt = 0; nt < 4; ++nt)
                #pragma unroll
                for (int r = 0; r < 4; ++r) {
                    float p = exp2f(sa[nt][r]);
                    sa[nt][r] = p;
                    li[g][r] += p;
                }
            #pragma unroll
            for (int r = 0; r < 4; ++r) {
                int qrow = quad * 4 + r;
                #pragma unroll
                for (int nt = 0; nt < 4; ++nt)
                    Ps[wv][qrow][nt * 16 + l15] = sa[nt][r];
            }
            float4 p0 = *(const float4*)&Ps[wv][l15][quad * 8];
            float4 p1 = *(const float4*)&Ps[wv][l15][quad * 8 + 4];
            float4 p2 = *(const float4*)&Ps[wv][l15][32 + quad * 8];
            float4 p3 = *(const float4*)&Ps[wv][l15][32 + quad * 8 + 4];
            union U8 { unsigned int u[4]; bf16x8 v8; };
            U8 ap0, ap1;
            ap0.u[0] = cvtpk(p0.x, p0.y); ap0.u[1] = cvtpk(p0.z, p0.w);
            ap0.u[2] = cvtpk(p1.x, p1.y); ap0.u[3] = cvtpk(p1.z, p1.w);
            ap1.u[0] = cvtpk(p2.x, p2.y); ap1.u[1] = cvtpk(p2.z, p2.w);
            ap1.u[2] = cvtpk(p3.x, p3.y); ap1.u[3] = cvtpk(p3.z, p3.w);
            #pragma unroll
            for (int nt = 0; nt < 4; ++nt) {
                oacc[g][nt] = __builtin_amdgcn_mfma_f32_16x16x32_bf16(ap0.v8, vf[nt][0], oacc[g][nt], 0, 0, 0);
                oacc[g][nt] = __builtin_amdgcn_mfma_f32_16x16x32_bf16(ap1.v8, vf[nt][1], oacc[g][nt], 0, 0, 0);
            }
        }
    };

    stage(Ks0, Vs0, 0);
    int kt = 0;
    while (true) {
        __syncthreads();
        if (kt + 1 < ktiles) stage(Ks1, Vs1, kt + 1);
        compute(Ks0, Vs0, kt);
        if (++kt >= ktiles) break;
        __syncthreads();
        if (kt + 1 < ktiles) stage(Ks0, Vs0, kt + 1);
        compute(Ks1, Vs1, kt);
        if (++kt >= ktiles) break;
    }

    #pragma unroll
    for (int g = 0; g < 2; ++g) {
        #pragma unroll
        for (int r = 0; r < 4; ++r) {
            float ls = li[g][r];
            ls += __shfl_xor(ls, 1);
            ls += __shfl_xor(ls, 2);
            ls += __shfl_xor(ls, 4);
            ls += __shfl_xor(ls, 8);
            float inv = (ls > 0.f) ? 1.0f / ls : 0.f;
            int srow = q0 + g * 16 + quad * 4 + r;
            #pragma unroll
            for (int nt = 0; nt < 4; ++nt) {
                int d = nt * 16 + l15;
                float val = qp[g][r] ? vmean[bh * Dd + d] : oacc[g][nt][r] * inv;
                ao[((size_t)b * Ss + srow) * HD + h * Dd + d] = f2bf(val);
            }
        }
    }
}

// ---------------------------------------------------------------------------
// Kernel 5: output projection, double-buffered glds staging.
// ---------------------------------------------------------------------------
__global__ __launch_bounds__(256) void gemm_out(
    const unsigned short* __restrict__ a_in, const unsigned short* __restrict__ Wt,
    const float* __restrict__ bo, float* __restrict__ out)
{
    const unsigned short* Wz = Wt + (size_t)3 * 262144;
    const int m0 = blockIdx.x * 128, n0 = blockIdx.y * 128;
    const int tid = threadIdx.x, lane = tid & 63, wv = tid >> 6;
    const int quad = lane >> 4, l15 = lane & 15;
    const int wm = (wv >> 1) * 64, wn = (wv & 1) * 64;

    __shared__ unsigned short As0[128][32], Bs0[128][32];
    __shared__ unsigned short As1[128][32], Bs1[128][32];

    f32x4 acc[4][4] = {};

    auto stage = [&](unsigned short (&A)[128][32], unsigned short (&B)[128][32], int k0) {
        #pragma unroll
        for (int l = 0; l < 2; ++l) {
            int ci = tid + l * 256;
            int r = ci >> 2, ch = (ci & 3) * 8;
            glds16(a_in + (size_t)(m0 + r) * HD + k0 + ch, &A[r][ch]);
            glds16(Wz + (size_t)(n0 + r) * HD + k0 + ch, &B[r][ch]);
        }
    };
    auto compute = [&](const unsigned short (&A)[128][32], const unsigned short (&B)[128][32]) {
        bf16x8 af[4], bfr[4];
        #pragma unroll
        for (int ms = 0; ms < 4; ++ms) af[ms] = *(const bf16x8*)&A[wm + ms * 16 + l15][quad * 8];
        #pragma unroll
        for (int ns = 0; ns < 4; ++ns) bfr[ns] = *(const bf16x8*)&B[wn + ns * 16 + l15][quad * 8];
        #pragma unroll
        for (int ms = 0; ms < 4; ++ms)
            #pragma unroll
            for (int ns = 0; ns < 4; ++ns)
                acc[ms][ns] = __builtin_amdgcn_mfma_f32_16x16x32_bf16(af[ms], bfr[ns], acc[ms][ns], 0, 0, 0);
    };

    stage(As0, Bs0, 0);
    for (int ki = 0; ki < 16; ki += 2) {
        __syncthreads();
        if (ki + 1 < 16) stage(As1, Bs1, (ki + 1) * 32);
        compute(As0, Bs0);
        __syncthreads();
        if (ki + 2 < 16) stage(As0, Bs0, (ki + 2) * 32);
        compute(As1, Bs1);
    }

    #pragma unroll
    for (int ns = 0; ns < 4; ++ns) {
        int col = n0 + wn + ns * 16 + l15;
        float bb = bo[col];
        #pragma unroll
        for (int ms = 0; ms < 4; ++ms) {
            #pragma unroll
            for (int r = 0; r < 4; ++r) {
                int m = m0 + wm + ms * 16 + quad * 4 + r;
                out[(size_t)m * Ee + col] = acc[ms][ns][r] + bb;
            }
        }
    }
}

extern "C" void kernel_launch(void* const* d_in, const int* in_sizes, int n_in,
                              void* d_out, int out_size, void* d_ws, size_t ws_size,
                              hipStream_t stream) {
    const float* x   = (const float*)d_in[0];
    const int*   pad = (const int*)  d_in[1];
    const float* Wq  = (const float*)d_in[2];
    const float* bq  = (const float*)d_in[3];
    const float* Wk  = (const float*)d_in[4];
    const float* bk  = (const float*)d_in[5];
    const float* Wv  = (const float*)d_in[6];
    const float* bv  = (const float*)d_in[7];
    const float* Wo  = (const float*)d_in[8];
    const float* bo  = (const float*)d_in[9];
    float* out = (float*)d_out;

    const size_t tsz = (size_t)Bb * Hh * Ss * Dd;       // 4,194,304 elems
    unsigned short* Wt  = (unsigned short*)d_ws;        // 1,048,576 shorts
    unsigned short* qb  = Wt + 1048576;
    unsigned short* kb  = qb + tsz;
    unsigned short* vb  = kb + tsz;
    unsigned short* kc  = vb + tsz;
    unsigned short* xb  = kc + tsz;                     // aliased: vtc after gemm_qkv
    unsigned short* vtc = xb;                           // xb dead once gemm_qkv done
    unsigned short* aob = kb;                           // kb dead after compact
    int* idxw   = (int*)(xb + tsz);
    int* cntw   = idxw + Bb * Ss;
    float* vmw  = (float*)(cntw + 4);

    prep<<<2308, 256, 0, stream>>>(x, pad, Wq, Wk, Wv, Wo, Wt, xb, idxw, cntw);

    dim3 g1(Mm / 128, HD / 128, 3);
    gemm_qkv<<<g1, 256, 0, stream>>>(xb, Wt, bq, bk, bv, qb, kb, vb);

    dim3 g2(33, Bb * Hh);
    compact_vmean<<<g2, 256, 0, stream>>>(kb, vb, idxw, cntw, kc, vtc, vmw);

    dim3 g3(Bb * Hh, Ss / 128);
    attn<<<g3, 256, 0, stream>>>(qb, kc, vtc, pad, cntw, vmw, aob);

    dim3 g4(Mm / 128, Ee / 128);
    gemm_out<<<g4, 256, 0, stream>>>(aob, Wt, bo, out);
}